// Round 1
// baseline (3571.791 us; speedup 1.0000x reference)
//
#include <hip/hip_runtime.h>
#include <hip/hip_bf16.h>
#include <math.h>

#define N_NODES 100000
#define N_EDGES 1000000
#define HALF_E  500000
#define H       128
#define NG      256
#define RELROWS 201
#define NH      (N_NODES * H)

// ---------------- degree / norm precompute ----------------
__global__ void deg_kernel(const int* __restrict__ ei, float* deg_in, float* deg_out) {
    int e = blockIdx.x * 256 + threadIdx.x;
    if (e >= N_EDGES) return;
    int src = ei[e];
    if (e < HALF_E) atomicAdd(deg_in + src, 1.0f);
    else            atomicAdd(deg_out + src, 1.0f);
}

__global__ void dinv_kernel(float* a, float* b) {
    int i = blockIdx.x * 256 + threadIdx.x;
    if (i >= N_NODES) return;
    float d = a[i]; a[i] = d > 0.f ? rsqrtf(d) : 0.f;
    d = b[i];       b[i] = d > 0.f ? rsqrtf(d) : 0.f;
}

__global__ void norm_kernel(const int* __restrict__ ei, const float* __restrict__ dinv_in,
                            const float* __restrict__ dinv_out, float* __restrict__ nrm) {
    int e = blockIdx.x * 256 + threadIdx.x;
    if (e >= N_EDGES) return;
    int s = ei[e], d = ei[N_EDGES + e];
    const float* dv = (e < HALF_E) ? dinv_in : dinv_out;
    nrm[e] = dv[s] * dv[d];
}

__global__ void cnt_kernel(const int* __restrict__ batch, float* cnt) {
    int i = blockIdx.x * 256 + threadIdx.x;
    if (i >= N_NODES) return;
    atomicAdd(cnt + batch[i], 1.0f);
}

// ---------------- rel chain (tiny) ----------------
__global__ void rel_build_kernel(const float* __restrict__ rge, const float* __restrict__ rbuf,
                                 const float* __restrict__ loop_rel, float* __restrict__ relA, int layer) {
    int i = blockIdx.x;      // 0..200
    int j = threadIdx.x;     // 0..127
    float v;
    if (i == 200)          v = loop_rel[j];
    else if (layer == 1)   v = (i < 100) ? rge[i * H + j] : -rge[(i - 100) * H + j];
    else                   v = rbuf[i * H + j];
    relA[i * H + j] = v;
}

__global__ void rel_mm_kernel(const float* __restrict__ relA,
                              const float* __restrict__ wIn, const float* __restrict__ wOut,
                              const float* __restrict__ wRel, const float* __restrict__ wLoop,
                              float* __restrict__ rwIn, float* __restrict__ rwOut,
                              float* __restrict__ rbuf, float* __restrict__ lwl) {
    __shared__ float a[H];
    int i = blockIdx.x, j = threadIdx.x;
    a[j] = relA[i * H + j];
    __syncthreads();
    float s_in = 0.f, s_out = 0.f, s_rel = 0.f, s_loop = 0.f;
    for (int k = 0; k < H; k++) {
        float av = a[k];
        s_in  += av * wIn [k * H + j];
        s_out += av * wOut[k * H + j];
        s_rel += av * wRel[k * H + j];
        s_loop += av * wLoop[k * H + j];
    }
    rwIn [i * H + j] = s_in;
    rwOut[i * H + j] = s_out;
    if (i < 200)  rbuf[i * H + j] = s_rel;
    if (i == 200) lwl[j] = s_loop;
}

// ---------------- node matmuls: Q=X@wIn, R=X@wOut, S=X@wLoop - lwl ----------------
__global__ __launch_bounds__(256) void mm_kernel(const float* __restrict__ X,
                                                 const float* __restrict__ wIn,
                                                 const float* __restrict__ wOut,
                                                 const float* __restrict__ wLoop,
                                                 const float* __restrict__ lwl,
                                                 float* __restrict__ Q, float* __restrict__ R,
                                                 float* __restrict__ S) {
    __shared__ float xt[32][H + 1];
    int tid = threadIdx.x;
    int row0 = blockIdx.x * 32;
    // stage 32 rows of X into LDS (must complete before any write: Q may alias X)
    const float4* Xv = (const float4*)(X + (size_t)row0 * H);
    for (int t = 0; t < 4; t++) {
        int idx = tid + t * 256;           // float4 index 0..1023
        float4 v = Xv[idx];
        int r = idx >> 5;
        int c = (idx & 31) * 4;
        xt[r][c] = v.x; xt[r][c + 1] = v.y; xt[r][c + 2] = v.z; xt[r][c + 3] = v.w;
    }
    __syncthreads();
    int cg = tid & 31;   // col group: cols 4*cg..4*cg+3
    int rg = tid >> 5;   // row group: rows 4*rg..4*rg+3

    const float* Ws[3] = { wIn, wOut, wLoop };
    float*       Os[3] = { Q, R, S };
    for (int wsel = 0; wsel < 3; wsel++) {
        const float* W = Ws[wsel];
        float acc[4][4] = {};
        for (int k = 0; k < H; k++) {
            float4 wv = *(const float4*)(W + k * H + cg * 4);
            float a0 = xt[rg * 4 + 0][k];
            float a1 = xt[rg * 4 + 1][k];
            float a2 = xt[rg * 4 + 2][k];
            float a3 = xt[rg * 4 + 3][k];
            acc[0][0] += a0 * wv.x; acc[0][1] += a0 * wv.y; acc[0][2] += a0 * wv.z; acc[0][3] += a0 * wv.w;
            acc[1][0] += a1 * wv.x; acc[1][1] += a1 * wv.y; acc[1][2] += a1 * wv.z; acc[1][3] += a1 * wv.w;
            acc[2][0] += a2 * wv.x; acc[2][1] += a2 * wv.y; acc[2][2] += a2 * wv.z; acc[2][3] += a2 * wv.w;
            acc[3][0] += a3 * wv.x; acc[3][1] += a3 * wv.y; acc[3][2] += a3 * wv.z; acc[3][3] += a3 * wv.w;
        }
        float4 sub = make_float4(0.f, 0.f, 0.f, 0.f);
        if (wsel == 2) sub = *(const float4*)(lwl + cg * 4);
        float* O = Os[wsel];
        for (int rr = 0; rr < 4; rr++) {
            float4 o = make_float4(acc[rr][0] - sub.x, acc[rr][1] - sub.y,
                                   acc[rr][2] - sub.z, acc[rr][3] - sub.w);
            *(float4*)(O + (size_t)(row0 + rg * 4 + rr) * H + cg * 4) = o;
        }
    }
}

// ---------------- edge scatter: S[dst] += (xw[src] - rw[etyp]) * norm ----------------
__global__ __launch_bounds__(256) void scatter_kernel(const float* __restrict__ Q, const float* __restrict__ R,
                                                      const float* __restrict__ rwIn, const float* __restrict__ rwOut,
                                                      const float* __restrict__ nrm, const int* __restrict__ ei,
                                                      const int* __restrict__ etype, float* __restrict__ S) {
    int gid = blockIdx.x * 256 + threadIdx.x;
    int e = gid >> 6;          // 64 lanes per edge
    int lane = gid & 63;
    if (e >= N_EDGES) return;
    int src = ei[e];
    int dst = ei[N_EDGES + e];
    int t = etype[e];
    float n = nrm[e];
    bool isin = (e < HALF_E);
    const float* Xw = isin ? Q : R;
    const float* Rw = isin ? rwIn : rwOut;
    int c = lane * 2;
    float2 xv = *(const float2*)(Xw + (size_t)src * H + c);
    float2 rv = *(const float2*)(Rw + (size_t)t * H + c);
    atomicAdd(S + (size_t)dst * H + c,     (xv.x - rv.x) * n);
    atomicAdd(S + (size_t)dst * H + c + 1, (xv.y - rv.y) * n);
}

// ---------------- combine: x' = tanh(S/3 + b), relu (mode 0) or pool (mode 1) ----------------
__global__ __launch_bounds__(256) void combine_kernel(const float* __restrict__ S, const float* __restrict__ b,
                                                      float* __restrict__ P, const int* __restrict__ batch,
                                                      float* __restrict__ pool, int mode) {
    int i = blockIdx.x * 256 + threadIdx.x;   // one thread per 2 cols
    int row = i >> 6;
    if (row >= N_NODES) return;
    int c = (i & 63) * 2;
    float2 s = *(const float2*)(S + (size_t)row * H + c);
    float v0 = tanhf(s.x * (1.f / 3.f) + b[c]);
    float v1 = tanhf(s.y * (1.f / 3.f) + b[c + 1]);
    if (mode == 0) {
        v0 = fmaxf(v0, 0.f); v1 = fmaxf(v1, 0.f);
        *(float2*)(P + (size_t)row * H + c) = make_float2(v0, v1);
    } else {
        int g = batch[row];
        atomicAdd(pool + g * H + c,     v0);
        atomicAdd(pool + g * H + c + 1, v1);
    }
}

// ---------------- final: out[g] = [mean, rel_emb] @ lin_w + lin_b ----------------
__global__ void final_kernel(const float* __restrict__ pool, const float* __restrict__ cnt,
                             const float* __restrict__ rel_table, const int* __restrict__ rel_labels,
                             const float* __restrict__ lin_w, const float* __restrict__ lin_b,
                             float* __restrict__ out) {
    int g = blockIdx.x;
    int lane = threadIdx.x;   // 64
    float inv = 1.f / fmaxf(cnt[g], 1.f);
    const float* rrow = rel_table + (size_t)rel_labels[g] * H;
    float p0 = 0.f, p1 = 0.f;
    for (int c = lane; c < H; c += 64) {
        float m = pool[g * H + c] * inv;
        p0 += m * lin_w[c * 2 + 0];
        p1 += m * lin_w[c * 2 + 1];
        float rv = rrow[c];
        p0 += rv * lin_w[(H + c) * 2 + 0];
        p1 += rv * lin_w[(H + c) * 2 + 1];
    }
    for (int off = 32; off; off >>= 1) {
        p0 += __shfl_down(p0, off);
        p1 += __shfl_down(p1, off);
    }
    if (lane == 0) {
        out[g * 2 + 0] = p0 + lin_b[0];
        out[g * 2 + 1] = p1 + lin_b[1];
    }
}

extern "C" void kernel_launch(void* const* d_in, const int* in_sizes, int n_in,
                              void* d_out, int out_size, void* d_ws, size_t ws_size,
                              hipStream_t stream) {
    const float* x          = (const float*)d_in[0];
    const int*   ei         = (const int*)  d_in[1];
    const int*   etype      = (const int*)  d_in[2];
    const int*   batch      = (const int*)  d_in[3];
    const int*   rel_labels = (const int*)  d_in[4];
    const float* rel_table  = (const float*)d_in[6];
    const float* rge        = (const float*)d_in[7];
    const float* lin_w      = (const float*)d_in[26];
    const float* lin_b      = (const float*)d_in[27];
    float* out = (float*)d_out;

    // workspace layout (floats)
    float* ws       = (float*)d_ws;
    float* P        = ws;                 // x-current / xw_in (aliased)
    float* R        = P + NH;             // xw_out
    float* S        = R + NH;             // accumulator
    float* nrm      = S + NH;             // [E]
    float* dinv_in  = nrm + N_EDGES;      // [N]
    float* dinv_out = dinv_in + N_NODES;  // [N]
    float* pool     = dinv_out + N_NODES; // [NG*H]
    float* cnt      = pool + NG * H;      // [NG]
    float* relA     = cnt + NG;           // [201*H]
    float* rbuf     = relA + RELROWS * H; // [200*H]
    float* rwIn     = rbuf + 200 * H;     // [3*201*H]
    float* rwOut    = rwIn + 3 * RELROWS * H;
    float* lwl      = rwOut + 3 * RELROWS * H;  // [3*H]

    // zero: dinv_in, dinv_out, pool, cnt (contiguous)
    hipMemsetAsync(dinv_in, 0, (size_t)(2 * N_NODES + NG * H + NG) * sizeof(float), stream);

    deg_kernel <<<(N_EDGES + 255) / 256, 256, 0, stream>>>(ei, dinv_in, dinv_out);
    dinv_kernel<<<(N_NODES + 255) / 256, 256, 0, stream>>>(dinv_in, dinv_out);
    norm_kernel<<<(N_EDGES + 255) / 256, 256, 0, stream>>>(ei, dinv_in, dinv_out, nrm);
    cnt_kernel <<<(N_NODES + 255) / 256, 256, 0, stream>>>(batch, cnt);

    // rel chain up-front
    for (int l = 0; l < 3; l++) {
        const float* wIn   = (const float*)d_in[8 + 6 * l + 0];
        const float* wOut  = (const float*)d_in[8 + 6 * l + 1];
        const float* wLoop = (const float*)d_in[8 + 6 * l + 2];
        const float* wRel  = (const float*)d_in[8 + 6 * l + 3];
        const float* lrel  = (const float*)d_in[8 + 6 * l + 4];
        rel_build_kernel<<<RELROWS, H, 0, stream>>>(rge, rbuf, lrel, relA, l + 1);
        rel_mm_kernel   <<<RELROWS, H, 0, stream>>>(relA, wIn, wOut, wRel, wLoop,
                                                    rwIn + l * RELROWS * H, rwOut + l * RELROWS * H,
                                                    rbuf, lwl + l * H);
    }

    // three conv layers
    for (int l = 0; l < 3; l++) {
        const float* wIn   = (const float*)d_in[8 + 6 * l + 0];
        const float* wOut  = (const float*)d_in[8 + 6 * l + 1];
        const float* wLoop = (const float*)d_in[8 + 6 * l + 2];
        const float* bl    = (const float*)d_in[8 + 6 * l + 5];
        const float* X     = (l == 0) ? x : P;
        mm_kernel<<<N_NODES / 32, 256, 0, stream>>>(X, wIn, wOut, wLoop, lwl + l * H, P, R, S);
        scatter_kernel<<<(N_EDGES * 64) / 256, 256, 0, stream>>>(P, R,
                                                                 rwIn + l * RELROWS * H, rwOut + l * RELROWS * H,
                                                                 nrm, ei, etype, S);
        combine_kernel<<<(N_NODES * 64) / 256, 256, 0, stream>>>(S, bl, P, batch, pool, (l == 2) ? 1 : 0);
    }

    final_kernel<<<NG, 64, 0, stream>>>(pool, cnt, rel_table, rel_labels, lin_w, lin_b, out);
}

// Round 2
// 1666.476 us; speedup vs baseline: 2.1433x; 2.1433x over previous
//
#include <hip/hip_runtime.h>
#include <hip/hip_bf16.h>
#include <math.h>

#define N_NODES 100000
#define N_EDGES 1000000
#define HALF_E  500000
#define H       128
#define NG      256
#define RELROWS 201
#define NH      (N_NODES * H)

// ---------------- degree (per-direction, over src) + dst histogram ----------------
__global__ void deg_hist_kernel(const int* __restrict__ ei, float* deg_in, float* deg_out,
                                int* __restrict__ cnt_dst) {
    int e = blockIdx.x * 256 + threadIdx.x;
    if (e >= N_EDGES) return;
    int src = ei[e];
    int dst = ei[N_EDGES + e];
    if (e < HALF_E) atomicAdd(deg_in + src, 1.0f);
    else            atomicAdd(deg_out + src, 1.0f);
    atomicAdd(cnt_dst + dst, 1);
}

__global__ void dinv_kernel(float* a, float* b) {
    int i = blockIdx.x * 256 + threadIdx.x;
    if (i >= N_NODES) return;
    float d = a[i]; a[i] = d > 0.f ? rsqrtf(d) : 0.f;
    d = b[i];       b[i] = d > 0.f ? rsqrtf(d) : 0.f;
}

// ---------------- exclusive scan over cnt_dst (single block) ----------------
__global__ __launch_bounds__(1024) void scan_kernel(const int* __restrict__ cnt,
                                                    int* __restrict__ rowptr,
                                                    int* __restrict__ rfill) {
    __shared__ int psum[1024];
    int t = threadIdx.x;
    const int CH = 98;  // 1024*98 >= 100000
    int begin = t * CH, end = min(begin + CH, N_NODES);
    int s = 0;
    for (int i = begin; i < end; i++) s += cnt[i];
    psum[t] = s;
    __syncthreads();
    for (int off = 1; off < 1024; off <<= 1) {
        int v = (t >= off) ? psum[t - off] : 0;
        __syncthreads();
        psum[t] += v;
        __syncthreads();
    }
    int run = (t == 0) ? 0 : psum[t - 1];
    for (int i = begin; i < end; i++) {
        rowptr[i] = run; rfill[i] = run;
        run += cnt[i];
    }
    if (t == 1023) rowptr[N_NODES] = run;
}

// ---------------- fill CSR: meta = (src + dir*N) | ((typ + dir*200) << 18), norm inline ----------------
__global__ void fill_kernel(const int* __restrict__ ei, const int* __restrict__ etype,
                            const float* __restrict__ dinv_in, const float* __restrict__ dinv_out,
                            int* __restrict__ rfill, int* __restrict__ meta,
                            float* __restrict__ csr_nrm) {
    int e = blockIdx.x * 256 + threadIdx.x;
    if (e >= N_EDGES) return;
    int s = ei[e], d = ei[N_EDGES + e];
    int t = etype[e];
    bool isin = (e < HALF_E);
    const float* dv = isin ? dinv_in : dinv_out;
    float nv = dv[s] * dv[d];
    int j = atomicAdd(rfill + d, 1);
    int src2 = s + (isin ? 0 : N_NODES);
    int typ2 = t + (isin ? 0 : 200);
    meta[j] = src2 | (typ2 << 18);
    csr_nrm[j] = nv;
}

__global__ void cnt_kernel(const int* __restrict__ batch, float* cnt) {
    int i = blockIdx.x * 256 + threadIdx.x;
    if (i >= N_NODES) return;
    atomicAdd(cnt + batch[i], 1.0f);
}

// ---------------- rel chain (tiny) ----------------
__global__ void rel_build_kernel(const float* __restrict__ rge, const float* __restrict__ rbuf,
                                 const float* __restrict__ loop_rel, float* __restrict__ relA, int layer) {
    int i = blockIdx.x;      // 0..200
    int j = threadIdx.x;     // 0..127
    float v;
    if (i == 200)          v = loop_rel[j];
    else if (layer == 1)   v = (i < 100) ? rge[i * H + j] : -rge[(i - 100) * H + j];
    else                   v = rbuf[i * H + j];
    relA[i * H + j] = v;
}

// RW layout per layer: rows 0..199 = rel@w_in, rows 200..399 = rel@w_out
__global__ void rel_mm_kernel(const float* __restrict__ relA,
                              const float* __restrict__ wIn, const float* __restrict__ wOut,
                              const float* __restrict__ wRel, const float* __restrict__ wLoop,
                              float* __restrict__ RW, float* __restrict__ rbuf,
                              float* __restrict__ lwl) {
    __shared__ float a[H];
    int i = blockIdx.x, j = threadIdx.x;
    a[j] = relA[i * H + j];
    __syncthreads();
    float s_in = 0.f, s_out = 0.f, s_rel = 0.f, s_loop = 0.f;
    for (int k = 0; k < H; k++) {
        float av = a[k];
        s_in  += av * wIn [k * H + j];
        s_out += av * wOut[k * H + j];
        s_rel += av * wRel[k * H + j];
        s_loop += av * wLoop[k * H + j];
    }
    if (i < 200) {
        RW[i * H + j] = s_in;
        RW[(200 + i) * H + j] = s_out;
        rbuf[i * H + j] = s_rel;
    }
    if (i == 200) lwl[j] = s_loop;
}

// ---------------- node matmuls: Q=X@wIn, R=X@wOut, S=X@wLoop - lwl ----------------
__global__ __launch_bounds__(256) void mm_kernel(const float* __restrict__ X,
                                                 const float* __restrict__ wIn,
                                                 const float* __restrict__ wOut,
                                                 const float* __restrict__ wLoop,
                                                 const float* __restrict__ lwl,
                                                 float* __restrict__ Q, float* __restrict__ R,
                                                 float* __restrict__ S) {
    __shared__ float xt[32][H + 1];
    int tid = threadIdx.x;
    int row0 = blockIdx.x * 32;
    // stage 32 rows of X into LDS (must complete before any write: S may alias X)
    const float4* Xv = (const float4*)(X + (size_t)row0 * H);
    for (int t = 0; t < 4; t++) {
        int idx = tid + t * 256;           // float4 index 0..1023
        float4 v = Xv[idx];
        int r = idx >> 5;
        int c = (idx & 31) * 4;
        xt[r][c] = v.x; xt[r][c + 1] = v.y; xt[r][c + 2] = v.z; xt[r][c + 3] = v.w;
    }
    __syncthreads();
    int cg = tid & 31;   // col group: cols 4*cg..4*cg+3
    int rg = tid >> 5;   // row group: rows 4*rg..4*rg+3

    const float* Ws[3] = { wIn, wOut, wLoop };
    float*       Os[3] = { Q, R, S };
    for (int wsel = 0; wsel < 3; wsel++) {
        const float* W = Ws[wsel];
        float acc[4][4] = {};
        for (int k = 0; k < H; k++) {
            float4 wv = *(const float4*)(W + k * H + cg * 4);
            float a0 = xt[rg * 4 + 0][k];
            float a1 = xt[rg * 4 + 1][k];
            float a2 = xt[rg * 4 + 2][k];
            float a3 = xt[rg * 4 + 3][k];
            acc[0][0] += a0 * wv.x; acc[0][1] += a0 * wv.y; acc[0][2] += a0 * wv.z; acc[0][3] += a0 * wv.w;
            acc[1][0] += a1 * wv.x; acc[1][1] += a1 * wv.y; acc[1][2] += a1 * wv.z; acc[1][3] += a1 * wv.w;
            acc[2][0] += a2 * wv.x; acc[2][1] += a2 * wv.y; acc[2][2] += a2 * wv.z; acc[2][3] += a2 * wv.w;
            acc[3][0] += a3 * wv.x; acc[3][1] += a3 * wv.y; acc[3][2] += a3 * wv.z; acc[3][3] += a3 * wv.w;
        }
        float4 sub = make_float4(0.f, 0.f, 0.f, 0.f);
        if (wsel == 2) sub = *(const float4*)(lwl + cg * 4);
        float* O = Os[wsel];
        for (int rr = 0; rr < 4; rr++) {
            float4 o = make_float4(acc[rr][0] - sub.x, acc[rr][1] - sub.y,
                                   acc[rr][2] - sub.z, acc[rr][3] - sub.w);
            *(float4*)(O + (size_t)(row0 + rg * 4 + rr) * H + cg * 4) = o;
        }
    }
}

// ---------------- gather + combine: one wave per dst node ----------------
// S[v] holds loop term on entry; on exit (mode 0) holds relu(tanh(...)) = next x.
// mode 1 (layer 3): atomicAdd tanh(...) into pool[batch[v]].
__global__ __launch_bounds__(256) void gather_kernel(const int* __restrict__ rowptr,
                                                     const int* __restrict__ meta,
                                                     const float* __restrict__ csr_nrm,
                                                     const float* __restrict__ QR,
                                                     const float* __restrict__ RW,
                                                     const float* __restrict__ b,
                                                     float* __restrict__ S,
                                                     const int* __restrict__ batch,
                                                     float* __restrict__ pool, int mode) {
    int v = blockIdx.x * 4 + (threadIdx.x >> 6);
    if (v >= N_NODES) return;
    int lane = threadIdx.x & 63;
    int c = lane * 2;
    int jb = rowptr[v], je = rowptr[v + 1];
    float2 acc = *(const float2*)(S + (size_t)v * H + c);   // loop term
    int j = jb;
    for (; j + 1 < je; j += 2) {
        int m0 = meta[j],     m1 = meta[j + 1];
        float n0 = csr_nrm[j], n1 = csr_nrm[j + 1];
        const float2 x0 = *(const float2*)(QR + (size_t)(m0 & 0x3FFFF) * H + c);
        const float2 r0 = *(const float2*)(RW + (size_t)(m0 >> 18) * H + c);
        const float2 x1 = *(const float2*)(QR + (size_t)(m1 & 0x3FFFF) * H + c);
        const float2 r1 = *(const float2*)(RW + (size_t)(m1 >> 18) * H + c);
        acc.x += (x0.x - r0.x) * n0; acc.y += (x0.y - r0.y) * n0;
        acc.x += (x1.x - r1.x) * n1; acc.y += (x1.y - r1.y) * n1;
    }
    if (j < je) {
        int m0 = meta[j];
        float n0 = csr_nrm[j];
        const float2 x0 = *(const float2*)(QR + (size_t)(m0 & 0x3FFFF) * H + c);
        const float2 r0 = *(const float2*)(RW + (size_t)(m0 >> 18) * H + c);
        acc.x += (x0.x - r0.x) * n0; acc.y += (x0.y - r0.y) * n0;
    }
    float v0 = tanhf(acc.x * (1.f / 3.f) + b[c]);
    float v1 = tanhf(acc.y * (1.f / 3.f) + b[c + 1]);
    if (mode == 0) {
        v0 = fmaxf(v0, 0.f); v1 = fmaxf(v1, 0.f);
        *(float2*)(S + (size_t)v * H + c) = make_float2(v0, v1);
    } else {
        int g = batch[v];
        atomicAdd(pool + g * H + c,     v0);
        atomicAdd(pool + g * H + c + 1, v1);
    }
}

// ---------------- final: out[g] = [mean, rel_emb] @ lin_w + lin_b ----------------
__global__ void final_kernel(const float* __restrict__ pool, const float* __restrict__ cnt,
                             const float* __restrict__ rel_table, const int* __restrict__ rel_labels,
                             const float* __restrict__ lin_w, const float* __restrict__ lin_b,
                             float* __restrict__ out) {
    int g = blockIdx.x;
    int lane = threadIdx.x;   // 64
    float inv = 1.f / fmaxf(cnt[g], 1.f);
    const float* rrow = rel_table + (size_t)rel_labels[g] * H;
    float p0 = 0.f, p1 = 0.f;
    for (int c = lane; c < H; c += 64) {
        float m = pool[g * H + c] * inv;
        p0 += m * lin_w[c * 2 + 0];
        p1 += m * lin_w[c * 2 + 1];
        float rv = rrow[c];
        p0 += rv * lin_w[(H + c) * 2 + 0];
        p1 += rv * lin_w[(H + c) * 2 + 1];
    }
    for (int off = 32; off; off >>= 1) {
        p0 += __shfl_down(p0, off);
        p1 += __shfl_down(p1, off);
    }
    if (lane == 0) {
        out[g * 2 + 0] = p0 + lin_b[0];
        out[g * 2 + 1] = p1 + lin_b[1];
    }
}

extern "C" void kernel_launch(void* const* d_in, const int* in_sizes, int n_in,
                              void* d_out, int out_size, void* d_ws, size_t ws_size,
                              hipStream_t stream) {
    const float* x          = (const float*)d_in[0];
    const int*   ei         = (const int*)  d_in[1];
    const int*   etype      = (const int*)  d_in[2];
    const int*   batch      = (const int*)  d_in[3];
    const int*   rel_labels = (const int*)  d_in[4];
    const float* rel_table  = (const float*)d_in[6];
    const float* rge        = (const float*)d_in[7];
    const float* lin_w      = (const float*)d_in[26];
    const float* lin_b      = (const float*)d_in[27];
    float* out = (float*)d_out;

    // ---- workspace layout ----
    float* ws       = (float*)d_ws;
    float* QR       = ws;                    // 2*NH  (Q = QR, R = QR + NH)
    float* S        = QR + 2 * (size_t)NH;   // NH (loop term -> next x)
    float* dinv_in  = S + NH;                // N
    float* dinv_out = dinv_in + N_NODES;     // N
    float* pool     = dinv_out + N_NODES;    // NG*H
    float* cnt      = pool + NG * H;         // NG
    float* relA     = cnt + NG;              // 201*H
    float* rbuf     = relA + RELROWS * H;    // 200*H
    float* RW       = rbuf + 200 * H;        // 3*400*H
    float* lwl      = RW + 3 * 400 * H;      // 3*H
    float* csr_nrm  = lwl + 3 * H;           // E
    int*   rowptr   = (int*)(csr_nrm + N_EDGES);  // N+1
    int*   rfill    = rowptr + N_NODES + 1;       // N
    int*   cnt_dst  = rfill + N_NODES;            // N
    int*   meta     = cnt_dst + N_NODES;          // E

    // zero: dinv_in, dinv_out, pool, cnt (contiguous floats); cnt_dst (ints)
    hipMemsetAsync(dinv_in, 0, (size_t)(2 * N_NODES + NG * H + NG) * sizeof(float), stream);
    hipMemsetAsync(cnt_dst, 0, (size_t)N_NODES * sizeof(int), stream);

    deg_hist_kernel<<<(N_EDGES + 255) / 256, 256, 0, stream>>>(ei, dinv_in, dinv_out, cnt_dst);
    dinv_kernel    <<<(N_NODES + 255) / 256, 256, 0, stream>>>(dinv_in, dinv_out);
    scan_kernel    <<<1, 1024, 0, stream>>>(cnt_dst, rowptr, rfill);
    fill_kernel    <<<(N_EDGES + 255) / 256, 256, 0, stream>>>(ei, etype, dinv_in, dinv_out,
                                                               rfill, meta, csr_nrm);
    cnt_kernel     <<<(N_NODES + 255) / 256, 256, 0, stream>>>(batch, cnt);

    // rel chain up-front
    for (int l = 0; l < 3; l++) {
        const float* wIn   = (const float*)d_in[8 + 6 * l + 0];
        const float* wOut  = (const float*)d_in[8 + 6 * l + 1];
        const float* wLoop = (const float*)d_in[8 + 6 * l + 2];
        const float* wRel  = (const float*)d_in[8 + 6 * l + 3];
        const float* lrel  = (const float*)d_in[8 + 6 * l + 4];
        rel_build_kernel<<<RELROWS, H, 0, stream>>>(rge, rbuf, lrel, relA, l + 1);
        rel_mm_kernel   <<<RELROWS, H, 0, stream>>>(relA, wIn, wOut, wRel, wLoop,
                                                    RW + (size_t)l * 400 * H, rbuf, lwl + l * H);
    }

    // three conv layers
    for (int l = 0; l < 3; l++) {
        const float* wIn   = (const float*)d_in[8 + 6 * l + 0];
        const float* wOut  = (const float*)d_in[8 + 6 * l + 1];
        const float* wLoop = (const float*)d_in[8 + 6 * l + 2];
        const float* bl    = (const float*)d_in[8 + 6 * l + 5];
        const float* X     = (l == 0) ? x : S;
        mm_kernel<<<N_NODES / 32, 256, 0, stream>>>(X, wIn, wOut, wLoop, lwl + l * H,
                                                    QR, QR + NH, S);
        gather_kernel<<<N_NODES / 4, 256, 0, stream>>>(rowptr, meta, csr_nrm,
                                                       QR, RW + (size_t)l * 400 * H, bl,
                                                       S, batch, pool, (l == 2) ? 1 : 0);
    }

    final_kernel<<<NG, 64, 0, stream>>>(pool, cnt, rel_table, rel_labels, lin_w, lin_b, out);
}

// Round 3
// 1452.439 us; speedup vs baseline: 2.4592x; 1.1474x over previous
//
#include <hip/hip_runtime.h>
#include <hip/hip_bf16.h>
#include <math.h>

#define N_NODES 100000
#define N_EDGES 1000000
#define HALF_E  500000
#define H       128
#define NG      256
#define RELROWS 201
#define NH      (N_NODES * H)
#define SCAN_NB 98   // 98 * 1024 >= 100000

// ---------------- degree (per-direction, over src) + dst histogram ----------------
__global__ void deg_hist_kernel(const int* __restrict__ ei, float* deg_in, float* deg_out,
                                int* __restrict__ cnt_dst) {
    int e = blockIdx.x * 256 + threadIdx.x;
    if (e >= N_EDGES) return;
    int src = ei[e];
    int dst = ei[N_EDGES + e];
    if (e < HALF_E) atomicAdd(deg_in + src, 1.0f);
    else            atomicAdd(deg_out + src, 1.0f);
    atomicAdd(cnt_dst + dst, 1);
}

__global__ void dinv_kernel(float* a, float* b) {
    int i = blockIdx.x * 256 + threadIdx.x;
    if (i >= N_NODES) return;
    float d = a[i]; a[i] = d > 0.f ? rsqrtf(d) : 0.f;
    d = b[i];       b[i] = d > 0.f ? rsqrtf(d) : 0.f;
}

// ---------------- 3-phase exclusive scan over cnt_dst ----------------
// phase 1: per-block exclusive scan (1024 elems/block), block sums out
__global__ __launch_bounds__(1024) void scan1_kernel(const int* __restrict__ cnt,
                                                     int* __restrict__ excl,
                                                     int* __restrict__ bsum) {
    __shared__ int ps[1024];
    int t = threadIdx.x;
    int i = blockIdx.x * 1024 + t;
    int v = (i < N_NODES) ? cnt[i] : 0;
    ps[t] = v;
    __syncthreads();
    for (int off = 1; off < 1024; off <<= 1) {
        int u = (t >= off) ? ps[t - off] : 0;
        __syncthreads();
        ps[t] += u;
        __syncthreads();
    }
    if (i < N_NODES) excl[i] = ps[t] - v;   // exclusive within block
    if (t == 1023) bsum[blockIdx.x] = ps[t];
}

// phase 2: scan the 98 block sums (single small block)
__global__ __launch_bounds__(128) void scan2_kernel(const int* __restrict__ bsum,
                                                    int* __restrict__ boff,
                                                    int* __restrict__ rowptr) {
    __shared__ int ps[128];
    int t = threadIdx.x;
    int v = (t < SCAN_NB) ? bsum[t] : 0;
    ps[t] = v;
    __syncthreads();
    for (int off = 1; off < 128; off <<= 1) {
        int u = (t >= off) ? ps[t - off] : 0;
        __syncthreads();
        ps[t] += u;
        __syncthreads();
    }
    if (t < SCAN_NB) boff[t] = ps[t] - v;   // exclusive
    if (t == 127) rowptr[N_NODES] = ps[t];  // total = N_EDGES
}

// phase 3: add block offsets, emit rowptr + rfill
__global__ __launch_bounds__(1024) void scan3_kernel(const int* __restrict__ excl,
                                                     const int* __restrict__ boff,
                                                     int* __restrict__ rowptr,
                                                     int* __restrict__ rfill) {
    int t = threadIdx.x;
    int i = blockIdx.x * 1024 + t;
    if (i >= N_NODES) return;
    int r = excl[i] + boff[blockIdx.x];
    rowptr[i] = r;
    rfill[i] = r;
}

// ---------------- fill CSR: meta = (src + dir*N) | ((typ + dir*200) << 18), norm inline ----------------
__global__ void fill_kernel(const int* __restrict__ ei, const int* __restrict__ etype,
                            const float* __restrict__ dinv_in, const float* __restrict__ dinv_out,
                            int* __restrict__ rfill, int* __restrict__ meta,
                            float* __restrict__ csr_nrm) {
    int e = blockIdx.x * 256 + threadIdx.x;
    if (e >= N_EDGES) return;
    int s = ei[e], d = ei[N_EDGES + e];
    int t = etype[e];
    bool isin = (e < HALF_E);
    const float* dv = isin ? dinv_in : dinv_out;
    float nv = dv[s] * dv[d];
    int j = atomicAdd(rfill + d, 1);
    int src2 = s + (isin ? 0 : N_NODES);
    int typ2 = t + (isin ? 0 : 200);
    meta[j] = src2 | (typ2 << 18);
    csr_nrm[j] = nv;
}

__global__ void cnt_kernel(const int* __restrict__ batch, float* cnt) {
    int i = blockIdx.x * 256 + threadIdx.x;
    if (i >= N_NODES) return;
    atomicAdd(cnt + batch[i], 1.0f);
}

// ---------------- rel chain (tiny) ----------------
__global__ void rel_build_kernel(const float* __restrict__ rge, const float* __restrict__ rbuf,
                                 const float* __restrict__ loop_rel, float* __restrict__ relA, int layer) {
    int i = blockIdx.x;      // 0..200
    int j = threadIdx.x;     // 0..127
    float v;
    if (i == 200)          v = loop_rel[j];
    else if (layer == 1)   v = (i < 100) ? rge[i * H + j] : -rge[(i - 100) * H + j];
    else                   v = rbuf[i * H + j];
    relA[i * H + j] = v;
}

// RW layout per layer: rows 0..199 = rel@w_in, rows 200..399 = rel@w_out
__global__ void rel_mm_kernel(const float* __restrict__ relA,
                              const float* __restrict__ wIn, const float* __restrict__ wOut,
                              const float* __restrict__ wRel, const float* __restrict__ wLoop,
                              float* __restrict__ RW, float* __restrict__ rbuf,
                              float* __restrict__ lwl) {
    __shared__ float a[H];
    int i = blockIdx.x, j = threadIdx.x;
    a[j] = relA[i * H + j];
    __syncthreads();
    float s_in = 0.f, s_out = 0.f, s_rel = 0.f, s_loop = 0.f;
    for (int k = 0; k < H; k++) {
        float av = a[k];
        s_in  += av * wIn [k * H + j];
        s_out += av * wOut[k * H + j];
        s_rel += av * wRel[k * H + j];
        s_loop += av * wLoop[k * H + j];
    }
    if (i < 200) {
        RW[i * H + j] = s_in;
        RW[(200 + i) * H + j] = s_out;
        rbuf[i * H + j] = s_rel;
    }
    if (i == 200) lwl[j] = s_loop;
}

// ---------------- node matmuls: Q=X@wIn, R=X@wOut, S=X@wLoop - lwl ----------------
__global__ __launch_bounds__(256) void mm_kernel(const float* __restrict__ X,
                                                 const float* __restrict__ wIn,
                                                 const float* __restrict__ wOut,
                                                 const float* __restrict__ wLoop,
                                                 const float* __restrict__ lwl,
                                                 float* __restrict__ Q, float* __restrict__ R,
                                                 float* __restrict__ S) {
    __shared__ float xt[32][H + 1];
    int tid = threadIdx.x;
    int row0 = blockIdx.x * 32;
    // stage 32 rows of X into LDS (must complete before any write: S may alias X)
    const float4* Xv = (const float4*)(X + (size_t)row0 * H);
    for (int t = 0; t < 4; t++) {
        int idx = tid + t * 256;           // float4 index 0..1023
        float4 v = Xv[idx];
        int r = idx >> 5;
        int c = (idx & 31) * 4;
        xt[r][c] = v.x; xt[r][c + 1] = v.y; xt[r][c + 2] = v.z; xt[r][c + 3] = v.w;
    }
    __syncthreads();
    int cg = tid & 31;   // col group: cols 4*cg..4*cg+3
    int rg = tid >> 5;   // row group: rows 4*rg..4*rg+3

    const float* Ws[3] = { wIn, wOut, wLoop };
    float*       Os[3] = { Q, R, S };
    for (int wsel = 0; wsel < 3; wsel++) {
        const float* W = Ws[wsel];
        float acc[4][4] = {};
        for (int k = 0; k < H; k++) {
            float4 wv = *(const float4*)(W + k * H + cg * 4);
            float a0 = xt[rg * 4 + 0][k];
            float a1 = xt[rg * 4 + 1][k];
            float a2 = xt[rg * 4 + 2][k];
            float a3 = xt[rg * 4 + 3][k];
            acc[0][0] += a0 * wv.x; acc[0][1] += a0 * wv.y; acc[0][2] += a0 * wv.z; acc[0][3] += a0 * wv.w;
            acc[1][0] += a1 * wv.x; acc[1][1] += a1 * wv.y; acc[1][2] += a1 * wv.z; acc[1][3] += a1 * wv.w;
            acc[2][0] += a2 * wv.x; acc[2][1] += a2 * wv.y; acc[2][2] += a2 * wv.z; acc[2][3] += a2 * wv.w;
            acc[3][0] += a3 * wv.x; acc[3][1] += a3 * wv.y; acc[3][2] += a3 * wv.z; acc[3][3] += a3 * wv.w;
        }
        float4 sub = make_float4(0.f, 0.f, 0.f, 0.f);
        if (wsel == 2) sub = *(const float4*)(lwl + cg * 4);
        float* O = Os[wsel];
        for (int rr = 0; rr < 4; rr++) {
            float4 o = make_float4(acc[rr][0] - sub.x, acc[rr][1] - sub.y,
                                   acc[rr][2] - sub.z, acc[rr][3] - sub.w);
            *(float4*)(O + (size_t)(row0 + rg * 4 + rr) * H + cg * 4) = o;
        }
    }
}

// ---------------- gather + combine: one wave per dst node ----------------
__global__ __launch_bounds__(256) void gather_kernel(const int* __restrict__ rowptr,
                                                     const int* __restrict__ meta,
                                                     const float* __restrict__ csr_nrm,
                                                     const float* __restrict__ QR,
                                                     const float* __restrict__ RW,
                                                     const float* __restrict__ b,
                                                     float* __restrict__ S,
                                                     const int* __restrict__ batch,
                                                     float* __restrict__ pool, int mode) {
    int v = blockIdx.x * 4 + (threadIdx.x >> 6);
    if (v >= N_NODES) return;
    int lane = threadIdx.x & 63;
    int c = lane * 2;
    int jb = rowptr[v], je = rowptr[v + 1];
    float2 acc = *(const float2*)(S + (size_t)v * H + c);   // loop term
    int j = jb;
    for (; j + 1 < je; j += 2) {
        int m0 = meta[j],     m1 = meta[j + 1];
        float n0 = csr_nrm[j], n1 = csr_nrm[j + 1];
        const float2 x0 = *(const float2*)(QR + (size_t)(m0 & 0x3FFFF) * H + c);
        const float2 r0 = *(const float2*)(RW + (size_t)(m0 >> 18) * H + c);
        const float2 x1 = *(const float2*)(QR + (size_t)(m1 & 0x3FFFF) * H + c);
        const float2 r1 = *(const float2*)(RW + (size_t)(m1 >> 18) * H + c);
        acc.x += (x0.x - r0.x) * n0; acc.y += (x0.y - r0.y) * n0;
        acc.x += (x1.x - r1.x) * n1; acc.y += (x1.y - r1.y) * n1;
    }
    if (j < je) {
        int m0 = meta[j];
        float n0 = csr_nrm[j];
        const float2 x0 = *(const float2*)(QR + (size_t)(m0 & 0x3FFFF) * H + c);
        const float2 r0 = *(const float2*)(RW + (size_t)(m0 >> 18) * H + c);
        acc.x += (x0.x - r0.x) * n0; acc.y += (x0.y - r0.y) * n0;
    }
    float v0 = tanhf(acc.x * (1.f / 3.f) + b[c]);
    float v1 = tanhf(acc.y * (1.f / 3.f) + b[c + 1]);
    if (mode == 0) {
        v0 = fmaxf(v0, 0.f); v1 = fmaxf(v1, 0.f);
        *(float2*)(S + (size_t)v * H + c) = make_float2(v0, v1);
    } else {
        int g = batch[v];
        atomicAdd(pool + g * H + c,     v0);
        atomicAdd(pool + g * H + c + 1, v1);
    }
}

// ---------------- final: out[g] = [mean, rel_emb] @ lin_w + lin_b ----------------
__global__ void final_kernel(const float* __restrict__ pool, const float* __restrict__ cnt,
                             const float* __restrict__ rel_table, const int* __restrict__ rel_labels,
                             const float* __restrict__ lin_w, const float* __restrict__ lin_b,
                             float* __restrict__ out) {
    int g = blockIdx.x;
    int lane = threadIdx.x;   // 64
    float inv = 1.f / fmaxf(cnt[g], 1.f);
    const float* rrow = rel_table + (size_t)rel_labels[g] * H;
    float p0 = 0.f, p1 = 0.f;
    for (int c = lane; c < H; c += 64) {
        float m = pool[g * H + c] * inv;
        p0 += m * lin_w[c * 2 + 0];
        p1 += m * lin_w[c * 2 + 1];
        float rv = rrow[c];
        p0 += rv * lin_w[(H + c) * 2 + 0];
        p1 += rv * lin_w[(H + c) * 2 + 1];
    }
    for (int off = 32; off; off >>= 1) {
        p0 += __shfl_down(p0, off);
        p1 += __shfl_down(p1, off);
    }
    if (lane == 0) {
        out[g * 2 + 0] = p0 + lin_b[0];
        out[g * 2 + 1] = p1 + lin_b[1];
    }
}

extern "C" void kernel_launch(void* const* d_in, const int* in_sizes, int n_in,
                              void* d_out, int out_size, void* d_ws, size_t ws_size,
                              hipStream_t stream) {
    const float* x          = (const float*)d_in[0];
    const int*   ei         = (const int*)  d_in[1];
    const int*   etype      = (const int*)  d_in[2];
    const int*   batch      = (const int*)  d_in[3];
    const int*   rel_labels = (const int*)  d_in[4];
    const float* rel_table  = (const float*)d_in[6];
    const float* rge        = (const float*)d_in[7];
    const float* lin_w      = (const float*)d_in[26];
    const float* lin_b      = (const float*)d_in[27];
    float* out = (float*)d_out;

    // ---- workspace layout ----
    float* ws       = (float*)d_ws;
    float* QR       = ws;                    // 2*NH  (Q = QR, R = QR + NH)
    float* S        = QR + 2 * (size_t)NH;   // NH (loop term -> next x)
    float* dinv_in  = S + NH;                // N
    float* dinv_out = dinv_in + N_NODES;     // N
    float* pool     = dinv_out + N_NODES;    // NG*H
    float* cnt      = pool + NG * H;         // NG
    float* relA     = cnt + NG;              // 201*H
    float* rbuf     = relA + RELROWS * H;    // 200*H
    float* RW       = rbuf + 200 * H;        // 3*400*H
    float* lwl      = RW + 3 * 400 * H;      // 3*H
    float* csr_nrm  = lwl + 3 * H;           // E
    int*   rowptr   = (int*)(csr_nrm + N_EDGES);  // N+1
    int*   rfill    = rowptr + N_NODES + 1;       // N
    int*   cnt_dst  = rfill + N_NODES;            // N
    int*   meta     = cnt_dst + N_NODES;          // E
    int*   excl     = meta + N_EDGES;             // N
    int*   bsum     = excl + N_NODES;             // SCAN_NB
    int*   boff     = bsum + SCAN_NB;             // SCAN_NB

    // zero: dinv_in, dinv_out, pool, cnt (contiguous floats); cnt_dst (ints)
    hipMemsetAsync(dinv_in, 0, (size_t)(2 * N_NODES + NG * H + NG) * sizeof(float), stream);
    hipMemsetAsync(cnt_dst, 0, (size_t)N_NODES * sizeof(int), stream);

    deg_hist_kernel<<<(N_EDGES + 255) / 256, 256, 0, stream>>>(ei, dinv_in, dinv_out, cnt_dst);
    dinv_kernel    <<<(N_NODES + 255) / 256, 256, 0, stream>>>(dinv_in, dinv_out);
    scan1_kernel   <<<SCAN_NB, 1024, 0, stream>>>(cnt_dst, excl, bsum);
    scan2_kernel   <<<1, 128, 0, stream>>>(bsum, boff, rowptr);
    scan3_kernel   <<<SCAN_NB, 1024, 0, stream>>>(excl, boff, rowptr, rfill);
    fill_kernel    <<<(N_EDGES + 255) / 256, 256, 0, stream>>>(ei, etype, dinv_in, dinv_out,
                                                               rfill, meta, csr_nrm);
    cnt_kernel     <<<(N_NODES + 255) / 256, 256, 0, stream>>>(batch, cnt);

    // rel chain up-front
    for (int l = 0; l < 3; l++) {
        const float* wIn   = (const float*)d_in[8 + 6 * l + 0];
        const float* wOut  = (const float*)d_in[8 + 6 * l + 1];
        const float* wLoop = (const float*)d_in[8 + 6 * l + 2];
        const float* wRel  = (const float*)d_in[8 + 6 * l + 3];
        const float* lrel  = (const float*)d_in[8 + 6 * l + 4];
        rel_build_kernel<<<RELROWS, H, 0, stream>>>(rge, rbuf, lrel, relA, l + 1);
        rel_mm_kernel   <<<RELROWS, H, 0, stream>>>(relA, wIn, wOut, wRel, wLoop,
                                                    RW + (size_t)l * 400 * H, rbuf, lwl + l * H);
    }

    // three conv layers
    for (int l = 0; l < 3; l++) {
        const float* wIn   = (const float*)d_in[8 + 6 * l + 0];
        const float* wOut  = (const float*)d_in[8 + 6 * l + 1];
        const float* wLoop = (const float*)d_in[8 + 6 * l + 2];
        const float* bl    = (const float*)d_in[8 + 6 * l + 5];
        const float* X     = (l == 0) ? x : S;
        mm_kernel<<<N_NODES / 32, 256, 0, stream>>>(X, wIn, wOut, wLoop, lwl + l * H,
                                                    QR, QR + NH, S);
        gather_kernel<<<N_NODES / 4, 256, 0, stream>>>(rowptr, meta, csr_nrm,
                                                       QR, RW + (size_t)l * 400 * H, bl,
                                                       S, batch, pool, (l == 2) ? 1 : 0);
    }

    final_kernel<<<NG, 64, 0, stream>>>(pool, cnt, rel_table, rel_labels, lin_w, lin_b, out);
}

// Round 4
// 1366.734 us; speedup vs baseline: 2.6134x; 1.0627x over previous
//
#include <hip/hip_runtime.h>
#include <hip/hip_bf16.h>
#include <math.h>

#define N_NODES 100000
#define N_EDGES 1000000
#define HALF_E  500000
#define H       128
#define NG      256
#define RELROWS 201
#define NH      (N_NODES * H)
#define SCAN_NB 98   // 98 * 1024 >= 100000

// ---- bf16 pack/unpack helpers (RNE) ----
__device__ __forceinline__ float bflo(unsigned p) { return __uint_as_float(p << 16); }
__device__ __forceinline__ float bfhi(unsigned p) { return __uint_as_float(p & 0xffff0000u); }
__device__ __forceinline__ unsigned packbf2(float a, float b) {
    unsigned ua = __float_as_uint(a), ub = __float_as_uint(b);
    ua = (ua + 0x7fffu + ((ua >> 16) & 1u)) >> 16;
    ub = (ub + 0x7fffu + ((ub >> 16) & 1u)) >> 16;
    return ua | (ub << 16);
}
__device__ __forceinline__ unsigned short packbf1(float a) {
    unsigned ua = __float_as_uint(a);
    return (unsigned short)((ua + 0x7fffu + ((ua >> 16) & 1u)) >> 16);
}

// ---------------- degree (per-direction, over src) + dst histogram ----------------
__global__ void deg_hist_kernel(const int* __restrict__ ei, float* deg_in, float* deg_out,
                                int* __restrict__ cnt_dst) {
    int e = blockIdx.x * 256 + threadIdx.x;
    if (e >= N_EDGES) return;
    int src = ei[e];
    int dst = ei[N_EDGES + e];
    if (e < HALF_E) atomicAdd(deg_in + src, 1.0f);
    else            atomicAdd(deg_out + src, 1.0f);
    atomicAdd(cnt_dst + dst, 1);
}

__global__ void dinv_kernel(float* a, float* b) {
    int i = blockIdx.x * 256 + threadIdx.x;
    if (i >= N_NODES) return;
    float d = a[i]; a[i] = d > 0.f ? rsqrtf(d) : 0.f;
    d = b[i];       b[i] = d > 0.f ? rsqrtf(d) : 0.f;
}

// ---------------- 3-phase exclusive scan over cnt_dst ----------------
__global__ __launch_bounds__(1024) void scan1_kernel(const int* __restrict__ cnt,
                                                     int* __restrict__ excl,
                                                     int* __restrict__ bsum) {
    __shared__ int ps[1024];
    int t = threadIdx.x;
    int i = blockIdx.x * 1024 + t;
    int v = (i < N_NODES) ? cnt[i] : 0;
    ps[t] = v;
    __syncthreads();
    for (int off = 1; off < 1024; off <<= 1) {
        int u = (t >= off) ? ps[t - off] : 0;
        __syncthreads();
        ps[t] += u;
        __syncthreads();
    }
    if (i < N_NODES) excl[i] = ps[t] - v;
    if (t == 1023) bsum[blockIdx.x] = ps[t];
}

__global__ __launch_bounds__(128) void scan2_kernel(const int* __restrict__ bsum,
                                                    int* __restrict__ boff,
                                                    int* __restrict__ rowptr) {
    __shared__ int ps[128];
    int t = threadIdx.x;
    int v = (t < SCAN_NB) ? bsum[t] : 0;
    ps[t] = v;
    __syncthreads();
    for (int off = 1; off < 128; off <<= 1) {
        int u = (t >= off) ? ps[t - off] : 0;
        __syncthreads();
        ps[t] += u;
        __syncthreads();
    }
    if (t < SCAN_NB) boff[t] = ps[t] - v;
    if (t == 127) rowptr[N_NODES] = ps[t];
}

__global__ __launch_bounds__(1024) void scan3_kernel(const int* __restrict__ excl,
                                                     const int* __restrict__ boff,
                                                     int* __restrict__ rowptr,
                                                     int* __restrict__ rfill) {
    int t = threadIdx.x;
    int i = blockIdx.x * 1024 + t;
    if (i >= N_NODES) return;
    int r = excl[i] + boff[blockIdx.x];
    rowptr[i] = r;
    rfill[i] = r;
}

// ---------------- fill CSR: meta = (src + dir*N) | ((typ + dir*200) << 18), norm inline ----------------
__global__ void fill_kernel(const int* __restrict__ ei, const int* __restrict__ etype,
                            const float* __restrict__ dinv_in, const float* __restrict__ dinv_out,
                            int* __restrict__ rfill, int* __restrict__ meta,
                            float* __restrict__ csr_nrm) {
    int e = blockIdx.x * 256 + threadIdx.x;
    if (e >= N_EDGES) return;
    int s = ei[e], d = ei[N_EDGES + e];
    int t = etype[e];
    bool isin = (e < HALF_E);
    const float* dv = isin ? dinv_in : dinv_out;
    float nv = dv[s] * dv[d];
    int j = atomicAdd(rfill + d, 1);
    int src2 = s + (isin ? 0 : N_NODES);
    int typ2 = t + (isin ? 0 : 200);
    meta[j] = src2 | (typ2 << 18);
    csr_nrm[j] = nv;
}

__global__ void cnt_kernel(const int* __restrict__ batch, float* cnt) {
    int i = blockIdx.x * 256 + threadIdx.x;
    if (i >= N_NODES) return;
    atomicAdd(cnt + batch[i], 1.0f);
}

// ---------------- rel chain (tiny) ----------------
__global__ void rel_build_kernel(const float* __restrict__ rge, const float* __restrict__ rbuf,
                                 const float* __restrict__ loop_rel, float* __restrict__ relA, int layer) {
    int i = blockIdx.x;      // 0..200
    int j = threadIdx.x;     // 0..127
    float v;
    if (i == 200)          v = loop_rel[j];
    else if (layer == 1)   v = (i < 100) ? rge[i * H + j] : -rge[(i - 100) * H + j];
    else                   v = rbuf[i * H + j];
    relA[i * H + j] = v;
}

// RWh layout per layer (bf16): rows 0..199 = rel@w_in, rows 200..399 = rel@w_out
__global__ void rel_mm_kernel(const float* __restrict__ relA,
                              const float* __restrict__ wIn, const float* __restrict__ wOut,
                              const float* __restrict__ wRel, const float* __restrict__ wLoop,
                              unsigned short* __restrict__ RWh, float* __restrict__ rbuf,
                              float* __restrict__ lwl) {
    __shared__ float a[H];
    int i = blockIdx.x, j = threadIdx.x;
    a[j] = relA[i * H + j];
    __syncthreads();
    float s_in = 0.f, s_out = 0.f, s_rel = 0.f, s_loop = 0.f;
    for (int k = 0; k < H; k++) {
        float av = a[k];
        s_in  += av * wIn [k * H + j];
        s_out += av * wOut[k * H + j];
        s_rel += av * wRel[k * H + j];
        s_loop += av * wLoop[k * H + j];
    }
    if (i < 200) {
        RWh[i * H + j] = packbf1(s_in);
        RWh[(200 + i) * H + j] = packbf1(s_out);
        rbuf[i * H + j] = s_rel;
    }
    if (i == 200) lwl[j] = s_loop;
}

// ---------------- node matmuls: Qh=X@wIn (bf16), Rh=X@wOut (bf16), S=X@wLoop - lwl (f32) ----------------
// Qh rows 0..N-1 and Rh rows N..2N-1 live in one buffer QRh (row = 64 uints).
__global__ __launch_bounds__(256) void mm_kernel(const float* __restrict__ X,
                                                 const float* __restrict__ wIn,
                                                 const float* __restrict__ wOut,
                                                 const float* __restrict__ wLoop,
                                                 const float* __restrict__ lwl,
                                                 unsigned* __restrict__ QRh,
                                                 float* __restrict__ S) {
    __shared__ float xt[32][H + 1];
    int tid = threadIdx.x;
    int row0 = blockIdx.x * 32;
    const float4* Xv = (const float4*)(X + (size_t)row0 * H);
    for (int t = 0; t < 4; t++) {
        int idx = tid + t * 256;
        float4 v = Xv[idx];
        int r = idx >> 5;
        int c = (idx & 31) * 4;
        xt[r][c] = v.x; xt[r][c + 1] = v.y; xt[r][c + 2] = v.z; xt[r][c + 3] = v.w;
    }
    __syncthreads();
    int cg = tid & 31;
    int rg = tid >> 5;

    const float* Ws[3] = { wIn, wOut, wLoop };
    for (int wsel = 0; wsel < 3; wsel++) {
        const float* W = Ws[wsel];
        float acc[4][4] = {};
        for (int k = 0; k < H; k++) {
            float4 wv = *(const float4*)(W + k * H + cg * 4);
            float a0 = xt[rg * 4 + 0][k];
            float a1 = xt[rg * 4 + 1][k];
            float a2 = xt[rg * 4 + 2][k];
            float a3 = xt[rg * 4 + 3][k];
            acc[0][0] += a0 * wv.x; acc[0][1] += a0 * wv.y; acc[0][2] += a0 * wv.z; acc[0][3] += a0 * wv.w;
            acc[1][0] += a1 * wv.x; acc[1][1] += a1 * wv.y; acc[1][2] += a1 * wv.z; acc[1][3] += a1 * wv.w;
            acc[2][0] += a2 * wv.x; acc[2][1] += a2 * wv.y; acc[2][2] += a2 * wv.z; acc[2][3] += a2 * wv.w;
            acc[3][0] += a3 * wv.x; acc[3][1] += a3 * wv.y; acc[3][2] += a3 * wv.z; acc[3][3] += a3 * wv.w;
        }
        if (wsel < 2) {
            size_t rbase = (size_t)(wsel == 0 ? 0 : N_NODES);
            for (int rr = 0; rr < 4; rr++) {
                unsigned p0 = packbf2(acc[rr][0], acc[rr][1]);
                unsigned p1 = packbf2(acc[rr][2], acc[rr][3]);
                uint2 pv = make_uint2(p0, p1);
                *(uint2*)(QRh + (rbase + row0 + rg * 4 + rr) * 64 + cg * 2) = pv;
            }
        } else {
            float4 sub = *(const float4*)(lwl + cg * 4);
            for (int rr = 0; rr < 4; rr++) {
                float4 o = make_float4(acc[rr][0] - sub.x, acc[rr][1] - sub.y,
                                       acc[rr][2] - sub.z, acc[rr][3] - sub.w);
                *(float4*)(S + (size_t)(row0 + rg * 4 + rr) * H + cg * 4) = o;
            }
        }
    }
}

// ---------------- gather + combine: one wave per dst node (bf16 gathers, 4x unroll) ----------------
__global__ __launch_bounds__(256) void gather_kernel(const int* __restrict__ rowptr,
                                                     const int* __restrict__ meta,
                                                     const float* __restrict__ csr_nrm,
                                                     const unsigned* __restrict__ QRh,
                                                     const unsigned* __restrict__ RWh,
                                                     const float* __restrict__ b,
                                                     float* __restrict__ S,
                                                     const int* __restrict__ batch,
                                                     float* __restrict__ pool, int mode) {
    int v = blockIdx.x * 4 + (threadIdx.x >> 6);
    if (v >= N_NODES) return;
    int lane = threadIdx.x & 63;
    int c = lane * 2;
    int jb = rowptr[v], je = rowptr[v + 1];
    float2 acc = *(const float2*)(S + (size_t)v * H + c);   // loop term
    int j = jb;
    for (; j + 3 < je; j += 4) {
        int m0 = meta[j], m1 = meta[j + 1], m2 = meta[j + 2], m3 = meta[j + 3];
        float n0 = csr_nrm[j], n1 = csr_nrm[j + 1], n2 = csr_nrm[j + 2], n3 = csr_nrm[j + 3];
        unsigned q0 = QRh[(size_t)(m0 & 0x3FFFF) * 64 + lane];
        unsigned r0 = RWh[(size_t)(m0 >> 18) * 64 + lane];
        unsigned q1 = QRh[(size_t)(m1 & 0x3FFFF) * 64 + lane];
        unsigned r1 = RWh[(size_t)(m1 >> 18) * 64 + lane];
        unsigned q2 = QRh[(size_t)(m2 & 0x3FFFF) * 64 + lane];
        unsigned r2 = RWh[(size_t)(m2 >> 18) * 64 + lane];
        unsigned q3 = QRh[(size_t)(m3 & 0x3FFFF) * 64 + lane];
        unsigned r3 = RWh[(size_t)(m3 >> 18) * 64 + lane];
        acc.x += (bflo(q0) - bflo(r0)) * n0; acc.y += (bfhi(q0) - bfhi(r0)) * n0;
        acc.x += (bflo(q1) - bflo(r1)) * n1; acc.y += (bfhi(q1) - bfhi(r1)) * n1;
        acc.x += (bflo(q2) - bflo(r2)) * n2; acc.y += (bfhi(q2) - bfhi(r2)) * n2;
        acc.x += (bflo(q3) - bflo(r3)) * n3; acc.y += (bfhi(q3) - bfhi(r3)) * n3;
    }
    for (; j < je; j++) {
        int m0 = meta[j];
        float n0 = csr_nrm[j];
        unsigned q0 = QRh[(size_t)(m0 & 0x3FFFF) * 64 + lane];
        unsigned r0 = RWh[(size_t)(m0 >> 18) * 64 + lane];
        acc.x += (bflo(q0) - bflo(r0)) * n0; acc.y += (bfhi(q0) - bfhi(r0)) * n0;
    }
    float v0 = tanhf(acc.x * (1.f / 3.f) + b[c]);
    float v1 = tanhf(acc.y * (1.f / 3.f) + b[c + 1]);
    if (mode == 0) {
        v0 = fmaxf(v0, 0.f); v1 = fmaxf(v1, 0.f);
        *(float2*)(S + (size_t)v * H + c) = make_float2(v0, v1);
    } else {
        int g = batch[v];
        atomicAdd(pool + g * H + c,     v0);
        atomicAdd(pool + g * H + c + 1, v1);
    }
}

// ---------------- final: out[g] = [mean, rel_emb] @ lin_w + lin_b ----------------
__global__ void final_kernel(const float* __restrict__ pool, const float* __restrict__ cnt,
                             const float* __restrict__ rel_table, const int* __restrict__ rel_labels,
                             const float* __restrict__ lin_w, const float* __restrict__ lin_b,
                             float* __restrict__ out) {
    int g = blockIdx.x;
    int lane = threadIdx.x;   // 64
    float inv = 1.f / fmaxf(cnt[g], 1.f);
    const float* rrow = rel_table + (size_t)rel_labels[g] * H;
    float p0 = 0.f, p1 = 0.f;
    for (int c = lane; c < H; c += 64) {
        float m = pool[g * H + c] * inv;
        p0 += m * lin_w[c * 2 + 0];
        p1 += m * lin_w[c * 2 + 1];
        float rv = rrow[c];
        p0 += rv * lin_w[(H + c) * 2 + 0];
        p1 += rv * lin_w[(H + c) * 2 + 1];
    }
    for (int off = 32; off; off >>= 1) {
        p0 += __shfl_down(p0, off);
        p1 += __shfl_down(p1, off);
    }
    if (lane == 0) {
        out[g * 2 + 0] = p0 + lin_b[0];
        out[g * 2 + 1] = p1 + lin_b[1];
    }
}

extern "C" void kernel_launch(void* const* d_in, const int* in_sizes, int n_in,
                              void* d_out, int out_size, void* d_ws, size_t ws_size,
                              hipStream_t stream) {
    const float* x          = (const float*)d_in[0];
    const int*   ei         = (const int*)  d_in[1];
    const int*   etype      = (const int*)  d_in[2];
    const int*   batch      = (const int*)  d_in[3];
    const int*   rel_labels = (const int*)  d_in[4];
    const float* rel_table  = (const float*)d_in[6];
    const float* rge        = (const float*)d_in[7];
    const float* lin_w      = (const float*)d_in[26];
    const float* lin_b      = (const float*)d_in[27];
    float* out = (float*)d_out;

    // ---- workspace layout ----
    float* ws       = (float*)d_ws;
    float* S        = ws;                    // NH (loop term -> next x)
    float* dinv_in  = S + NH;                // N
    float* dinv_out = dinv_in + N_NODES;     // N
    float* pool     = dinv_out + N_NODES;    // NG*H
    float* cnt      = pool + NG * H;         // NG
    float* relA     = cnt + NG;              // 201*H
    float* rbuf     = relA + RELROWS * H;    // 200*H
    float* lwl      = rbuf + 200 * H;        // 3*H
    float* csr_nrm  = lwl + 3 * H;           // E
    int*   rowptr   = (int*)(csr_nrm + N_EDGES);  // N+1
    int*   rfill    = rowptr + N_NODES + 1;       // N
    int*   cnt_dst  = rfill + N_NODES;            // N
    int*   meta     = cnt_dst + N_NODES;          // E
    int*   excl     = meta + N_EDGES;             // N
    int*   bsum     = excl + N_NODES;             // SCAN_NB
    int*   boff     = bsum + SCAN_NB;             // SCAN_NB (+ pad to even)
    unsigned* QRh   = (unsigned*)(boff + SCAN_NB + 2);  // NH uints (Q rows 0..N-1, R rows N..2N-1)
    unsigned* RWh   = QRh + (size_t)NH;                 // 3 * 400 * 64 uints

    // zero: dinv_in, dinv_out, pool, cnt (contiguous floats); cnt_dst (ints)
    hipMemsetAsync(dinv_in, 0, (size_t)(2 * N_NODES + NG * H + NG) * sizeof(float), stream);
    hipMemsetAsync(cnt_dst, 0, (size_t)N_NODES * sizeof(int), stream);

    deg_hist_kernel<<<(N_EDGES + 255) / 256, 256, 0, stream>>>(ei, dinv_in, dinv_out, cnt_dst);
    dinv_kernel    <<<(N_NODES + 255) / 256, 256, 0, stream>>>(dinv_in, dinv_out);
    scan1_kernel   <<<SCAN_NB, 1024, 0, stream>>>(cnt_dst, excl, bsum);
    scan2_kernel   <<<1, 128, 0, stream>>>(bsum, boff, rowptr);
    scan3_kernel   <<<SCAN_NB, 1024, 0, stream>>>(excl, boff, rowptr, rfill);
    fill_kernel    <<<(N_EDGES + 255) / 256, 256, 0, stream>>>(ei, etype, dinv_in, dinv_out,
                                                               rfill, meta, csr_nrm);
    cnt_kernel     <<<(N_NODES + 255) / 256, 256, 0, stream>>>(batch, cnt);

    // rel chain up-front
    for (int l = 0; l < 3; l++) {
        const float* wIn   = (const float*)d_in[8 + 6 * l + 0];
        const float* wOut  = (const float*)d_in[8 + 6 * l + 1];
        const float* wLoop = (const float*)d_in[8 + 6 * l + 2];
        const float* wRel  = (const float*)d_in[8 + 6 * l + 3];
        const float* lrel  = (const float*)d_in[8 + 6 * l + 4];
        rel_build_kernel<<<RELROWS, H, 0, stream>>>(rge, rbuf, lrel, relA, l + 1);
        rel_mm_kernel   <<<RELROWS, H, 0, stream>>>(relA, wIn, wOut, wRel, wLoop,
                                                    (unsigned short*)(RWh + (size_t)l * 400 * 64),
                                                    rbuf, lwl + l * H);
    }

    // three conv layers
    for (int l = 0; l < 3; l++) {
        const float* wIn   = (const float*)d_in[8 + 6 * l + 0];
        const float* wOut  = (const float*)d_in[8 + 6 * l + 1];
        const float* wLoop = (const float*)d_in[8 + 6 * l + 2];
        const float* bl    = (const float*)d_in[8 + 6 * l + 5];
        const float* X     = (l == 0) ? x : S;
        mm_kernel<<<N_NODES / 32, 256, 0, stream>>>(X, wIn, wOut, wLoop, lwl + l * H,
                                                    QRh, S);
        gather_kernel<<<N_NODES / 4, 256, 0, stream>>>(rowptr, meta, csr_nrm,
                                                       QRh, RWh + (size_t)l * 400 * 64, bl,
                                                       S, batch, pool, (l == 2) ? 1 : 0);
    }

    final_kernel<<<NG, 64, 0, stream>>>(pool, cnt, rel_table, rel_labels, lin_w, lin_b, out);
}

// Round 5
// 1173.431 us; speedup vs baseline: 3.0439x; 1.1647x over previous
//
#include <hip/hip_runtime.h>
#include <hip/hip_bf16.h>
#include <math.h>

#define N_NODES 100000
#define N_EDGES 1000000
#define HALF_E  500000
#define H       128
#define NG      256
#define RELROWS 201
#define NH      (N_NODES * H)
#define SCAN_NB 98   // 98 * 1024 >= 100000

// ---- bf16 pack/unpack helpers (RNE) ----
__device__ __forceinline__ float bflo(unsigned p) { return __uint_as_float(p << 16); }
__device__ __forceinline__ float bfhi(unsigned p) { return __uint_as_float(p & 0xffff0000u); }
__device__ __forceinline__ unsigned packbf2(float a, float b) {
    unsigned ua = __float_as_uint(a), ub = __float_as_uint(b);
    ua = (ua + 0x7fffu + ((ua >> 16) & 1u)) >> 16;
    ub = (ub + 0x7fffu + ((ub >> 16) & 1u)) >> 16;
    return ua | (ub << 16);
}
__device__ __forceinline__ unsigned short packbf1(float a) {
    unsigned ua = __float_as_uint(a);
    return (unsigned short)((ua + 0x7fffu + ((ua >> 16) & 1u)) >> 16);
}

// ---------------- degree (per-direction, over src) + dst histogram ----------------
__global__ void deg_hist_kernel(const int* __restrict__ ei, float* deg_in, float* deg_out,
                                int* __restrict__ cnt_dst) {
    int e = blockIdx.x * 256 + threadIdx.x;
    if (e >= N_EDGES) return;
    int src = ei[e];
    int dst = ei[N_EDGES + e];
    if (e < HALF_E) atomicAdd(deg_in + src, 1.0f);
    else            atomicAdd(deg_out + src, 1.0f);
    atomicAdd(cnt_dst + dst, 1);
}

__global__ void dinv_kernel(float* a, float* b) {
    int i = blockIdx.x * 256 + threadIdx.x;
    if (i >= N_NODES) return;
    float d = a[i]; a[i] = d > 0.f ? rsqrtf(d) : 0.f;
    d = b[i];       b[i] = d > 0.f ? rsqrtf(d) : 0.f;
}

// ---------------- 3-phase exclusive scan over cnt_dst ----------------
__global__ __launch_bounds__(1024) void scan1_kernel(const int* __restrict__ cnt,
                                                     int* __restrict__ excl,
                                                     int* __restrict__ bsum) {
    __shared__ int ps[1024];
    int t = threadIdx.x;
    int i = blockIdx.x * 1024 + t;
    int v = (i < N_NODES) ? cnt[i] : 0;
    ps[t] = v;
    __syncthreads();
    for (int off = 1; off < 1024; off <<= 1) {
        int u = (t >= off) ? ps[t - off] : 0;
        __syncthreads();
        ps[t] += u;
        __syncthreads();
    }
    if (i < N_NODES) excl[i] = ps[t] - v;
    if (t == 1023) bsum[blockIdx.x] = ps[t];
}

__global__ __launch_bounds__(128) void scan2_kernel(const int* __restrict__ bsum,
                                                    int* __restrict__ boff,
                                                    int* __restrict__ rowptr) {
    __shared__ int ps[128];
    int t = threadIdx.x;
    int v = (t < SCAN_NB) ? bsum[t] : 0;
    ps[t] = v;
    __syncthreads();
    for (int off = 1; off < 128; off <<= 1) {
        int u = (t >= off) ? ps[t - off] : 0;
        __syncthreads();
        ps[t] += u;
        __syncthreads();
    }
    if (t < SCAN_NB) boff[t] = ps[t] - v;
    if (t == 127) rowptr[N_NODES] = ps[t];
}

__global__ __launch_bounds__(1024) void scan3_kernel(const int* __restrict__ excl,
                                                     const int* __restrict__ boff,
                                                     int* __restrict__ rowptr,
                                                     int* __restrict__ rfill) {
    int t = threadIdx.x;
    int i = blockIdx.x * 1024 + t;
    if (i >= N_NODES) return;
    int r = excl[i] + boff[blockIdx.x];
    rowptr[i] = r;
    rfill[i] = r;
}

// ---------------- fill CSR: meta = (src + dir*N) | ((typ + dir*200) << 18), norm inline ----------------
__global__ void fill_kernel(const int* __restrict__ ei, const int* __restrict__ etype,
                            const float* __restrict__ dinv_in, const float* __restrict__ dinv_out,
                            int* __restrict__ rfill, int* __restrict__ meta,
                            float* __restrict__ csr_nrm) {
    int e = blockIdx.x * 256 + threadIdx.x;
    if (e >= N_EDGES) return;
    int s = ei[e], d = ei[N_EDGES + e];
    int t = etype[e];
    bool isin = (e < HALF_E);
    const float* dv = isin ? dinv_in : dinv_out;
    float nv = dv[s] * dv[d];
    int j = atomicAdd(rfill + d, 1);
    int src2 = s + (isin ? 0 : N_NODES);
    int typ2 = t + (isin ? 0 : 200);
    meta[j] = src2 | (typ2 << 18);
    csr_nrm[j] = nv;
}

// ---------------- per-graph node counts via binary search (batch is sorted) ----------------
__global__ void cnt_bs_kernel(const int* __restrict__ batch, float* __restrict__ cnt) {
    int g = blockIdx.x * 64 + threadIdx.x;
    if (g >= NG) return;
    int lo = 0, hi = N_NODES;
    while (lo < hi) { int mid = (lo + hi) >> 1; if (batch[mid] < g) lo = mid + 1; else hi = mid; }
    int start = lo;
    lo = 0; hi = N_NODES;
    while (lo < hi) { int mid = (lo + hi) >> 1; if (batch[mid] < g + 1) lo = mid + 1; else hi = mid; }
    cnt[g] = (float)(lo - start);
}

// ---------------- rel chain (tiny) ----------------
__global__ void rel_build_kernel(const float* __restrict__ rge, const float* __restrict__ rbuf,
                                 const float* __restrict__ loop_rel, float* __restrict__ relA, int layer) {
    int i = blockIdx.x;      // 0..200
    int j = threadIdx.x;     // 0..127
    float v;
    if (i == 200)          v = loop_rel[j];
    else if (layer == 1)   v = (i < 100) ? rge[i * H + j] : -rge[(i - 100) * H + j];
    else                   v = rbuf[i * H + j];
    relA[i * H + j] = v;
}

// RWh layout per layer (bf16): rows 0..199 = rel@w_in, rows 200..399 = rel@w_out
__global__ void rel_mm_kernel(const float* __restrict__ relA,
                              const float* __restrict__ wIn, const float* __restrict__ wOut,
                              const float* __restrict__ wRel, const float* __restrict__ wLoop,
                              unsigned short* __restrict__ RWh, float* __restrict__ rbuf,
                              float* __restrict__ lwl) {
    __shared__ float a[H];
    int i = blockIdx.x, j = threadIdx.x;
    a[j] = relA[i * H + j];
    __syncthreads();
    float s_in = 0.f, s_out = 0.f, s_rel = 0.f, s_loop = 0.f;
    for (int k = 0; k < H; k++) {
        float av = a[k];
        s_in  += av * wIn [k * H + j];
        s_out += av * wOut[k * H + j];
        s_rel += av * wRel[k * H + j];
        s_loop += av * wLoop[k * H + j];
    }
    if (i < 200) {
        RWh[i * H + j] = packbf1(s_in);
        RWh[(200 + i) * H + j] = packbf1(s_out);
        rbuf[i * H + j] = s_rel;
    }
    if (i == 200) lwl[j] = s_loop;
}

// ---------------- node matmuls: Qh=X@wIn (bf16), Rh=X@wOut (bf16), S=X@wLoop - lwl (f32) ----------------
__global__ __launch_bounds__(256) void mm_kernel(const float* __restrict__ X,
                                                 const float* __restrict__ wIn,
                                                 const float* __restrict__ wOut,
                                                 const float* __restrict__ wLoop,
                                                 const float* __restrict__ lwl,
                                                 unsigned* __restrict__ QRh,
                                                 float* __restrict__ S) {
    __shared__ float xt[32][H + 1];
    int tid = threadIdx.x;
    int row0 = blockIdx.x * 32;
    const float4* Xv = (const float4*)(X + (size_t)row0 * H);
    for (int t = 0; t < 4; t++) {
        int idx = tid + t * 256;
        float4 v = Xv[idx];
        int r = idx >> 5;
        int c = (idx & 31) * 4;
        xt[r][c] = v.x; xt[r][c + 1] = v.y; xt[r][c + 2] = v.z; xt[r][c + 3] = v.w;
    }
    __syncthreads();
    int cg = tid & 31;
    int rg = tid >> 5;

    const float* Ws[3] = { wIn, wOut, wLoop };
    for (int wsel = 0; wsel < 3; wsel++) {
        const float* W = Ws[wsel];
        float acc[4][4] = {};
        for (int k = 0; k < H; k++) {
            float4 wv = *(const float4*)(W + k * H + cg * 4);
            float a0 = xt[rg * 4 + 0][k];
            float a1 = xt[rg * 4 + 1][k];
            float a2 = xt[rg * 4 + 2][k];
            float a3 = xt[rg * 4 + 3][k];
            acc[0][0] += a0 * wv.x; acc[0][1] += a0 * wv.y; acc[0][2] += a0 * wv.z; acc[0][3] += a0 * wv.w;
            acc[1][0] += a1 * wv.x; acc[1][1] += a1 * wv.y; acc[1][2] += a1 * wv.z; acc[1][3] += a1 * wv.w;
            acc[2][0] += a2 * wv.x; acc[2][1] += a2 * wv.y; acc[2][2] += a2 * wv.z; acc[2][3] += a2 * wv.w;
            acc[3][0] += a3 * wv.x; acc[3][1] += a3 * wv.y; acc[3][2] += a3 * wv.z; acc[3][3] += a3 * wv.w;
        }
        if (wsel < 2) {
            size_t rbase = (size_t)(wsel == 0 ? 0 : N_NODES);
            for (int rr = 0; rr < 4; rr++) {
                unsigned p0 = packbf2(acc[rr][0], acc[rr][1]);
                unsigned p1 = packbf2(acc[rr][2], acc[rr][3]);
                uint2 pv = make_uint2(p0, p1);
                *(uint2*)(QRh + (rbase + row0 + rg * 4 + rr) * 64 + cg * 2) = pv;
            }
        } else {
            float4 sub = *(const float4*)(lwl + cg * 4);
            for (int rr = 0; rr < 4; rr++) {
                float4 o = make_float4(acc[rr][0] - sub.x, acc[rr][1] - sub.y,
                                       acc[rr][2] - sub.z, acc[rr][3] - sub.w);
                *(float4*)(S + (size_t)(row0 + rg * 4 + rr) * H + cg * 4) = o;
            }
        }
    }
}

// ---------------- gather + combine: one wave per dst node (bf16 gathers, 4x unroll) ----------------
__global__ __launch_bounds__(256) void gather_kernel(const int* __restrict__ rowptr,
                                                     const int* __restrict__ meta,
                                                     const float* __restrict__ csr_nrm,
                                                     const unsigned* __restrict__ QRh,
                                                     const unsigned* __restrict__ RWh,
                                                     const float* __restrict__ b,
                                                     float* __restrict__ S,
                                                     const int* __restrict__ batch,
                                                     float* __restrict__ pool, int mode) {
    int v = blockIdx.x * 4 + (threadIdx.x >> 6);
    if (v >= N_NODES) return;
    int lane = threadIdx.x & 63;
    int c = lane * 2;
    int jb = rowptr[v], je = rowptr[v + 1];
    float2 acc = *(const float2*)(S + (size_t)v * H + c);   // loop term
    int j = jb;
    for (; j + 3 < je; j += 4) {
        int m0 = meta[j], m1 = meta[j + 1], m2 = meta[j + 2], m3 = meta[j + 3];
        float n0 = csr_nrm[j], n1 = csr_nrm[j + 1], n2 = csr_nrm[j + 2], n3 = csr_nrm[j + 3];
        unsigned q0 = QRh[(size_t)(m0 & 0x3FFFF) * 64 + lane];
        unsigned r0 = RWh[(size_t)(m0 >> 18) * 64 + lane];
        unsigned q1 = QRh[(size_t)(m1 & 0x3FFFF) * 64 + lane];
        unsigned r1 = RWh[(size_t)(m1 >> 18) * 64 + lane];
        unsigned q2 = QRh[(size_t)(m2 & 0x3FFFF) * 64 + lane];
        unsigned r2 = RWh[(size_t)(m2 >> 18) * 64 + lane];
        unsigned q3 = QRh[(size_t)(m3 & 0x3FFFF) * 64 + lane];
        unsigned r3 = RWh[(size_t)(m3 >> 18) * 64 + lane];
        acc.x += (bflo(q0) - bflo(r0)) * n0; acc.y += (bfhi(q0) - bfhi(r0)) * n0;
        acc.x += (bflo(q1) - bflo(r1)) * n1; acc.y += (bfhi(q1) - bfhi(r1)) * n1;
        acc.x += (bflo(q2) - bflo(r2)) * n2; acc.y += (bfhi(q2) - bfhi(r2)) * n2;
        acc.x += (bflo(q3) - bflo(r3)) * n3; acc.y += (bfhi(q3) - bfhi(r3)) * n3;
    }
    for (; j < je; j++) {
        int m0 = meta[j];
        float n0 = csr_nrm[j];
        unsigned q0 = QRh[(size_t)(m0 & 0x3FFFF) * 64 + lane];
        unsigned r0 = RWh[(size_t)(m0 >> 18) * 64 + lane];
        acc.x += (bflo(q0) - bflo(r0)) * n0; acc.y += (bfhi(q0) - bfhi(r0)) * n0;
    }
    float v0 = tanhf(acc.x * (1.f / 3.f) + b[c]);
    float v1 = tanhf(acc.y * (1.f / 3.f) + b[c + 1]);
    if (mode == 0) {
        v0 = fmaxf(v0, 0.f); v1 = fmaxf(v1, 0.f);
        *(float2*)(S + (size_t)v * H + c) = make_float2(v0, v1);
    } else {
        int g = batch[v];
        atomicAdd(pool + g * H + c,     v0);
        atomicAdd(pool + g * H + c + 1, v1);
    }
}

// ---------------- final: out[g] = [mean, rel_emb] @ lin_w + lin_b ----------------
__global__ void final_kernel(const float* __restrict__ pool, const float* __restrict__ cnt,
                             const float* __restrict__ rel_table, const int* __restrict__ rel_labels,
                             const float* __restrict__ lin_w, const float* __restrict__ lin_b,
                             float* __restrict__ out) {
    int g = blockIdx.x;
    int lane = threadIdx.x;   // 64
    float inv = 1.f / fmaxf(cnt[g], 1.f);
    const float* rrow = rel_table + (size_t)rel_labels[g] * H;
    float p0 = 0.f, p1 = 0.f;
    for (int c = lane; c < H; c += 64) {
        float m = pool[g * H + c] * inv;
        p0 += m * lin_w[c * 2 + 0];
        p1 += m * lin_w[c * 2 + 1];
        float rv = rrow[c];
        p0 += rv * lin_w[(H + c) * 2 + 0];
        p1 += rv * lin_w[(H + c) * 2 + 1];
    }
    for (int off = 32; off; off >>= 1) {
        p0 += __shfl_down(p0, off);
        p1 += __shfl_down(p1, off);
    }
    if (lane == 0) {
        out[g * 2 + 0] = p0 + lin_b[0];
        out[g * 2 + 1] = p1 + lin_b[1];
    }
}

extern "C" void kernel_launch(void* const* d_in, const int* in_sizes, int n_in,
                              void* d_out, int out_size, void* d_ws, size_t ws_size,
                              hipStream_t stream) {
    const float* x          = (const float*)d_in[0];
    const int*   ei         = (const int*)  d_in[1];
    const int*   etype      = (const int*)  d_in[2];
    const int*   batch      = (const int*)  d_in[3];
    const int*   rel_labels = (const int*)  d_in[4];
    const float* rel_table  = (const float*)d_in[6];
    const float* rge        = (const float*)d_in[7];
    const float* lin_w      = (const float*)d_in[26];
    const float* lin_b      = (const float*)d_in[27];
    float* out = (float*)d_out;

    // ---- workspace layout ----
    float* ws       = (float*)d_ws;
    float* S        = ws;                    // NH (loop term -> next x)
    float* dinv_in  = S + NH;                // N
    float* dinv_out = dinv_in + N_NODES;     // N
    float* pool     = dinv_out + N_NODES;    // NG*H
    float* cnt      = pool + NG * H;         // NG
    float* relA     = cnt + NG;              // 201*H
    float* rbuf     = relA + RELROWS * H;    // 200*H
    float* lwl      = rbuf + 200 * H;        // 3*H
    float* csr_nrm  = lwl + 3 * H;           // E
    int*   rowptr   = (int*)(csr_nrm + N_EDGES);  // N+1
    int*   rfill    = rowptr + N_NODES + 1;       // N
    int*   cnt_dst  = rfill + N_NODES;            // N
    int*   meta     = cnt_dst + N_NODES;          // E
    int*   excl     = meta + N_EDGES;             // N
    int*   bsum     = excl + N_NODES;             // SCAN_NB
    int*   boff     = bsum + SCAN_NB;             // SCAN_NB (+ pad to even)
    unsigned* QRh   = (unsigned*)(boff + SCAN_NB + 2);  // NH uints (Q rows 0..N-1, R rows N..2N-1)
    unsigned* RWh   = QRh + (size_t)NH;                 // 3 * 400 * 64 uints

    // zero: dinv_in, dinv_out, pool, cnt (contiguous floats); cnt_dst (ints)
    hipMemsetAsync(dinv_in, 0, (size_t)(2 * N_NODES + NG * H + NG) * sizeof(float), stream);
    hipMemsetAsync(cnt_dst, 0, (size_t)N_NODES * sizeof(int), stream);

    deg_hist_kernel<<<(N_EDGES + 255) / 256, 256, 0, stream>>>(ei, dinv_in, dinv_out, cnt_dst);
    dinv_kernel    <<<(N_NODES + 255) / 256, 256, 0, stream>>>(dinv_in, dinv_out);
    scan1_kernel   <<<SCAN_NB, 1024, 0, stream>>>(cnt_dst, excl, bsum);
    scan2_kernel   <<<1, 128, 0, stream>>>(bsum, boff, rowptr);
    scan3_kernel   <<<SCAN_NB, 1024, 0, stream>>>(excl, boff, rowptr, rfill);
    fill_kernel    <<<(N_EDGES + 255) / 256, 256, 0, stream>>>(ei, etype, dinv_in, dinv_out,
                                                               rfill, meta, csr_nrm);
    cnt_bs_kernel  <<<NG / 64, 64, 0, stream>>>(batch, cnt);

    // rel chain up-front
    for (int l = 0; l < 3; l++) {
        const float* wIn   = (const float*)d_in[8 + 6 * l + 0];
        const float* wOut  = (const float*)d_in[8 + 6 * l + 1];
        const float* wLoop = (const float*)d_in[8 + 6 * l + 2];
        const float* wRel  = (const float*)d_in[8 + 6 * l + 3];
        const float* lrel  = (const float*)d_in[8 + 6 * l + 4];
        rel_build_kernel<<<RELROWS, H, 0, stream>>>(rge, rbuf, lrel, relA, l + 1);
        rel_mm_kernel   <<<RELROWS, H, 0, stream>>>(relA, wIn, wOut, wRel, wLoop,
                                                    (unsigned short*)(RWh + (size_t)l * 400 * 64),
                                                    rbuf, lwl + l * H);
    }

    // three conv layers
    for (int l = 0; l < 3; l++) {
        const float* wIn   = (const float*)d_in[8 + 6 * l + 0];
        const float* wOut  = (const float*)d_in[8 + 6 * l + 1];
        const float* wLoop = (const float*)d_in[8 + 6 * l + 2];
        const float* bl    = (const float*)d_in[8 + 6 * l + 5];
        const float* X     = (l == 0) ? x : S;
        mm_kernel<<<N_NODES / 32, 256, 0, stream>>>(X, wIn, wOut, wLoop, lwl + l * H,
                                                    QRh, S);
        gather_kernel<<<N_NODES / 4, 256, 0, stream>>>(rowptr, meta, csr_nrm,
                                                       QRh, RWh + (size_t)l * 400 * 64, bl,
                                                       S, batch, pool, (l == 2) ? 1 : 0);
    }

    final_kernel<<<NG, 64, 0, stream>>>(pool, cnt, rel_table, rel_labels, lin_w, lin_b, out);
}

// Round 6
// 771.153 us; speedup vs baseline: 4.6318x; 1.5217x over previous
//
#include <hip/hip_runtime.h>
#include <hip/hip_bf16.h>
#include <math.h>

#define N_NODES 100000
#define N_EDGES 1000000
#define HALF_E  500000
#define H       128
#define NG      256
#define RELROWS 201
#define NH      (N_NODES * H)
#define SCAN_NB 98   // 98 * 1024 >= 100000
#define XPITCH  136  // 128 + 8 bf16 pad (breaks LDS bank aliasing)
#define MMB     64   // X rows per mm block

typedef __attribute__((ext_vector_type(8))) short bf16x8;
typedef __attribute__((ext_vector_type(4))) float f32x4;

// ---- bf16 pack/unpack helpers (RNE) ----
__device__ __forceinline__ float bflo(unsigned p) { return __uint_as_float(p << 16); }
__device__ __forceinline__ float bfhi(unsigned p) { return __uint_as_float(p & 0xffff0000u); }
__device__ __forceinline__ unsigned packbf2(float a, float b) {
    unsigned ua = __float_as_uint(a), ub = __float_as_uint(b);
    ua = (ua + 0x7fffu + ((ua >> 16) & 1u)) >> 16;
    ub = (ub + 0x7fffu + ((ub >> 16) & 1u)) >> 16;
    return ua | (ub << 16);
}
__device__ __forceinline__ unsigned short packbf1(float a) {
    unsigned ua = __float_as_uint(a);
    return (unsigned short)((ua + 0x7fffu + ((ua >> 16) & 1u)) >> 16);
}

// ---------------- degree (per-direction, over src) + dst histogram ----------------
__global__ void deg_hist_kernel(const int* __restrict__ ei, float* deg_in, float* deg_out,
                                int* __restrict__ cnt_dst) {
    int e = blockIdx.x * 256 + threadIdx.x;
    if (e >= N_EDGES) return;
    int src = ei[e];
    int dst = ei[N_EDGES + e];
    if (e < HALF_E) atomicAdd(deg_in + src, 1.0f);
    else            atomicAdd(deg_out + src, 1.0f);
    atomicAdd(cnt_dst + dst, 1);
}

__global__ void dinv_kernel(float* a, float* b) {
    int i = blockIdx.x * 256 + threadIdx.x;
    if (i >= N_NODES) return;
    float d = a[i]; a[i] = d > 0.f ? rsqrtf(d) : 0.f;
    d = b[i];       b[i] = d > 0.f ? rsqrtf(d) : 0.f;
}

// ---------------- 3-phase exclusive scan over cnt_dst ----------------
__global__ __launch_bounds__(1024) void scan1_kernel(const int* __restrict__ cnt,
                                                     int* __restrict__ excl,
                                                     int* __restrict__ bsum) {
    __shared__ int ps[1024];
    int t = threadIdx.x;
    int i = blockIdx.x * 1024 + t;
    int v = (i < N_NODES) ? cnt[i] : 0;
    ps[t] = v;
    __syncthreads();
    for (int off = 1; off < 1024; off <<= 1) {
        int u = (t >= off) ? ps[t - off] : 0;
        __syncthreads();
        ps[t] += u;
        __syncthreads();
    }
    if (i < N_NODES) excl[i] = ps[t] - v;
    if (t == 1023) bsum[blockIdx.x] = ps[t];
}

__global__ __launch_bounds__(128) void scan2_kernel(const int* __restrict__ bsum,
                                                    int* __restrict__ boff,
                                                    int* __restrict__ rowptr) {
    __shared__ int ps[128];
    int t = threadIdx.x;
    int v = (t < SCAN_NB) ? bsum[t] : 0;
    ps[t] = v;
    __syncthreads();
    for (int off = 1; off < 128; off <<= 1) {
        int u = (t >= off) ? ps[t - off] : 0;
        __syncthreads();
        ps[t] += u;
        __syncthreads();
    }
    if (t < SCAN_NB) boff[t] = ps[t] - v;
    if (t == 127) rowptr[N_NODES] = ps[t];
}

__global__ __launch_bounds__(1024) void scan3_kernel(const int* __restrict__ excl,
                                                     const int* __restrict__ boff,
                                                     int* __restrict__ rowptr,
                                                     int* __restrict__ rfill) {
    int t = threadIdx.x;
    int i = blockIdx.x * 1024 + t;
    if (i >= N_NODES) return;
    int r = excl[i] + boff[blockIdx.x];
    rowptr[i] = r;
    rfill[i] = r;
}

// ---------------- fill CSR: meta = (src + dir*N) | ((typ + dir*200) << 18), norm inline ----------------
__global__ void fill_kernel(const int* __restrict__ ei, const int* __restrict__ etype,
                            const float* __restrict__ dinv_in, const float* __restrict__ dinv_out,
                            int* __restrict__ rfill, int* __restrict__ meta,
                            float* __restrict__ csr_nrm) {
    int e = blockIdx.x * 256 + threadIdx.x;
    if (e >= N_EDGES) return;
    int s = ei[e], d = ei[N_EDGES + e];
    int t = etype[e];
    bool isin = (e < HALF_E);
    const float* dv = isin ? dinv_in : dinv_out;
    float nv = dv[s] * dv[d];
    int j = atomicAdd(rfill + d, 1);
    int src2 = s + (isin ? 0 : N_NODES);
    int typ2 = t + (isin ? 0 : 200);
    meta[j] = src2 | (typ2 << 18);
    csr_nrm[j] = nv;
}

// ---------------- per-graph node counts via binary search (batch is sorted) ----------------
__global__ void cnt_bs_kernel(const int* __restrict__ batch, float* __restrict__ cnt) {
    int g = blockIdx.x * 64 + threadIdx.x;
    if (g >= NG) return;
    int lo = 0, hi = N_NODES;
    while (lo < hi) { int mid = (lo + hi) >> 1; if (batch[mid] < g) lo = mid + 1; else hi = mid; }
    int start = lo;
    lo = 0; hi = N_NODES;
    while (lo < hi) { int mid = (lo + hi) >> 1; if (batch[mid] < g + 1) lo = mid + 1; else hi = mid; }
    cnt[g] = (float)(lo - start);
}

// ---------------- rel chain (tiny) ----------------
__global__ void rel_build_kernel(const float* __restrict__ rge, const float* __restrict__ rbuf,
                                 const float* __restrict__ loop_rel, float* __restrict__ relA, int layer) {
    int i = blockIdx.x;      // 0..200
    int j = threadIdx.x;     // 0..127
    float v;
    if (i == 200)          v = loop_rel[j];
    else if (layer == 1)   v = (i < 100) ? rge[i * H + j] : -rge[(i - 100) * H + j];
    else                   v = rbuf[i * H + j];
    relA[i * H + j] = v;
}

// RWh layout per layer (bf16): rows 0..199 = rel@w_in, rows 200..399 = rel@w_out
__global__ void rel_mm_kernel(const float* __restrict__ relA,
                              const float* __restrict__ wIn, const float* __restrict__ wOut,
                              const float* __restrict__ wRel, const float* __restrict__ wLoop,
                              unsigned short* __restrict__ RWh, float* __restrict__ rbuf,
                              float* __restrict__ lwl) {
    __shared__ float a[H];
    int i = blockIdx.x, j = threadIdx.x;
    a[j] = relA[i * H + j];
    __syncthreads();
    float s_in = 0.f, s_out = 0.f, s_rel = 0.f, s_loop = 0.f;
    for (int k = 0; k < H; k++) {
        float av = a[k];
        s_in  += av * wIn [k * H + j];
        s_out += av * wOut[k * H + j];
        s_rel += av * wRel[k * H + j];
        s_loop += av * wLoop[k * H + j];
    }
    if (i < 200) {
        RWh[i * H + j] = packbf1(s_in);
        RWh[(200 + i) * H + j] = packbf1(s_out);
        rbuf[i * H + j] = s_rel;
    }
    if (i == 200) lwl[j] = s_loop;
}

// ---------------- weight pre-pack into MFMA B-fragment order (bf16) ----------------
// Bpack[iw][nt][kk][lane][j] = bf16(W[(kk*32 + (lane>>4)*8 + j)*H + nt*16 + (lane&15)])
struct WPtrs { const float* p[9]; };
__global__ __launch_bounds__(256) void wpack_kernel(WPtrs wp, unsigned short* __restrict__ Bp) {
    int iw = blockIdx.y;  // l*3 + w
    const float* W = wp.p[iw];
    unsigned short* out = Bp + (size_t)iw * 16384;
    int t = blockIdx.x * 256 + threadIdx.x;   // 0..2047
    int nt = t >> 8, kk = (t >> 6) & 3, lane = t & 63;
    int n = nt * 16 + (lane & 15);
    int k0 = kk * 32 + (lane >> 4) * 8;
    unsigned p[4];
    for (int j = 0; j < 4; j++)
        p[j] = packbf2(W[(k0 + 2 * j) * H + n], W[(k0 + 2 * j + 1) * H + n]);
    *(uint4*)(out + ((size_t)(nt * 4 + kk) * 64 + lane) * 8) = make_uint4(p[0], p[1], p[2], p[3]);
}

// ---------------- MFMA node matmuls: Qh=X@wIn, Rh=X@wOut (bf16), Sb=X@wLoop - lwl (bf16) ----------------
__global__ __launch_bounds__(256) void mm_mfma_kernel(const float* __restrict__ Xf,
                                                      const unsigned short* __restrict__ Xh,
                                                      int xf32,
                                                      const unsigned short* __restrict__ Bpack,
                                                      const float* __restrict__ lwl,
                                                      unsigned short* __restrict__ QRh,
                                                      unsigned short* __restrict__ Sb) {
    __shared__ unsigned short xt[MMB * XPITCH];
    int tid = threadIdx.x;
    int row0 = blockIdx.x * MMB;
    int nrows = min(MMB, N_NODES - row0);
    if (xf32) {
        for (int t = 0; t < 8; t++) {
            int idx = tid + t * 256;                 // 2048 float4s
            int r = idx >> 5, c4 = (idx & 31) * 4;
            if (r < nrows) {
                float4 v = *(const float4*)(Xf + (size_t)(row0 + r) * H + c4);
                *(uint2*)(xt + r * XPITCH + c4) = make_uint2(packbf2(v.x, v.y), packbf2(v.z, v.w));
            }
        }
    } else {
        for (int t = 0; t < 4; t++) {
            int idx = tid + t * 256;                 // 1024 uint4s (8 bf16 each)
            int r = idx >> 4, c8 = (idx & 15) * 8;
            if (r < nrows)
                *(uint4*)(xt + r * XPITCH + c8) = *(const uint4*)(Xh + (size_t)(row0 + r) * H + c8);
        }
    }
    __syncthreads();

    int wave = tid >> 6, lane = tid & 63;
    int m0w = wave * 16;
    int q = lane >> 4, ml = lane & 15;
    bf16x8 afrag[4];
    for (int kk = 0; kk < 4; kk++)
        afrag[kk] = *(const bf16x8*)(xt + (m0w + ml) * XPITCH + kk * 32 + q * 8);
    int grow_base = row0 + m0w + q * 4;
    for (int w = 0; w < 3; w++) {
        for (int nt = 0; nt < 8; nt++) {
            const unsigned short* bp = Bpack + (((size_t)(w * 8 + nt) * 4) * 64 + lane) * 8;
            f32x4 acc = {0.f, 0.f, 0.f, 0.f};
            for (int kk = 0; kk < 4; kk++) {
                bf16x8 bfrag = *(const bf16x8*)(bp + (size_t)kk * 512);
                acc = __builtin_amdgcn_mfma_f32_16x16x32_bf16(afrag[kk], bfrag, acc, 0, 0, 0);
            }
            int col = nt * 16 + ml;
            if (w < 2) {
                size_t rbase = (w == 0) ? 0 : (size_t)N_NODES;
                for (int reg = 0; reg < 4; reg++) {
                    int grow = grow_base + reg;
                    if (grow < N_NODES)
                        QRh[(rbase + grow) * H + col] = packbf1(acc[reg]);
                }
            } else {
                float sub = lwl[col];
                for (int reg = 0; reg < 4; reg++) {
                    int grow = grow_base + reg;
                    if (grow < N_NODES)
                        Sb[(size_t)grow * H + col] = packbf1(acc[reg] - sub);
                }
            }
        }
    }
}

// ---------------- gather + combine: one wave per dst node (bf16, 4x unroll) ----------------
__global__ __launch_bounds__(256) void gather_kernel(const int* __restrict__ rowptr,
                                                     const int* __restrict__ meta,
                                                     const float* __restrict__ csr_nrm,
                                                     const unsigned* __restrict__ QRh,
                                                     const unsigned* __restrict__ RWh,
                                                     const float* __restrict__ b,
                                                     unsigned* __restrict__ Sb,
                                                     const int* __restrict__ batch,
                                                     float* __restrict__ pool, int mode) {
    int v = blockIdx.x * 4 + (threadIdx.x >> 6);
    if (v >= N_NODES) return;
    int lane = threadIdx.x & 63;
    int c = lane * 2;
    int jb = rowptr[v], je = rowptr[v + 1];
    unsigned sv = Sb[(size_t)v * 64 + lane];
    float2 acc = make_float2(bflo(sv), bfhi(sv));   // loop term
    int j = jb;
    for (; j + 3 < je; j += 4) {
        int m0 = meta[j], m1 = meta[j + 1], m2 = meta[j + 2], m3 = meta[j + 3];
        float n0 = csr_nrm[j], n1 = csr_nrm[j + 1], n2 = csr_nrm[j + 2], n3 = csr_nrm[j + 3];
        unsigned q0 = QRh[(size_t)(m0 & 0x3FFFF) * 64 + lane];
        unsigned r0 = RWh[(size_t)(m0 >> 18) * 64 + lane];
        unsigned q1 = QRh[(size_t)(m1 & 0x3FFFF) * 64 + lane];
        unsigned r1 = RWh[(size_t)(m1 >> 18) * 64 + lane];
        unsigned q2 = QRh[(size_t)(m2 & 0x3FFFF) * 64 + lane];
        unsigned r2 = RWh[(size_t)(m2 >> 18) * 64 + lane];
        unsigned q3 = QRh[(size_t)(m3 & 0x3FFFF) * 64 + lane];
        unsigned r3 = RWh[(size_t)(m3 >> 18) * 64 + lane];
        acc.x += (bflo(q0) - bflo(r0)) * n0; acc.y += (bfhi(q0) - bfhi(r0)) * n0;
        acc.x += (bflo(q1) - bflo(r1)) * n1; acc.y += (bfhi(q1) - bfhi(r1)) * n1;
        acc.x += (bflo(q2) - bflo(r2)) * n2; acc.y += (bfhi(q2) - bfhi(r2)) * n2;
        acc.x += (bflo(q3) - bflo(r3)) * n3; acc.y += (bfhi(q3) - bfhi(r3)) * n3;
    }
    for (; j < je; j++) {
        int m0 = meta[j];
        float n0 = csr_nrm[j];
        unsigned q0 = QRh[(size_t)(m0 & 0x3FFFF) * 64 + lane];
        unsigned r0 = RWh[(size_t)(m0 >> 18) * 64 + lane];
        acc.x += (bflo(q0) - bflo(r0)) * n0; acc.y += (bfhi(q0) - bfhi(r0)) * n0;
    }
    float v0 = tanhf(acc.x * (1.f / 3.f) + b[c]);
    float v1 = tanhf(acc.y * (1.f / 3.f) + b[c + 1]);
    if (mode == 0) {
        v0 = fmaxf(v0, 0.f); v1 = fmaxf(v1, 0.f);
        Sb[(size_t)v * 64 + lane] = packbf2(v0, v1);
    } else {
        int g = batch[v];
        atomicAdd(pool + g * H + c,     v0);
        atomicAdd(pool + g * H + c + 1, v1);
    }
}

// ---------------- final: out[g] = [mean, rel_emb] @ lin_w + lin_b ----------------
__global__ void final_kernel(const float* __restrict__ pool, const float* __restrict__ cnt,
                             const float* __restrict__ rel_table, const int* __restrict__ rel_labels,
                             const float* __restrict__ lin_w, const float* __restrict__ lin_b,
                             float* __restrict__ out) {
    int g = blockIdx.x;
    int lane = threadIdx.x;   // 64
    float inv = 1.f / fmaxf(cnt[g], 1.f);
    const float* rrow = rel_table + (size_t)rel_labels[g] * H;
    float p0 = 0.f, p1 = 0.f;
    for (int c = lane; c < H; c += 64) {
        float m = pool[g * H + c] * inv;
        p0 += m * lin_w[c * 2 + 0];
        p1 += m * lin_w[c * 2 + 1];
        float rv = rrow[c];
        p0 += rv * lin_w[(H + c) * 2 + 0];
        p1 += rv * lin_w[(H + c) * 2 + 1];
    }
    for (int off = 32; off; off >>= 1) {
        p0 += __shfl_down(p0, off);
        p1 += __shfl_down(p1, off);
    }
    if (lane == 0) {
        out[g * 2 + 0] = p0 + lin_b[0];
        out[g * 2 + 1] = p1 + lin_b[1];
    }
}

extern "C" void kernel_launch(void* const* d_in, const int* in_sizes, int n_in,
                              void* d_out, int out_size, void* d_ws, size_t ws_size,
                              hipStream_t stream) {
    const float* x          = (const float*)d_in[0];
    const int*   ei         = (const int*)  d_in[1];
    const int*   etype      = (const int*)  d_in[2];
    const int*   batch      = (const int*)  d_in[3];
    const int*   rel_labels = (const int*)  d_in[4];
    const float* rel_table  = (const float*)d_in[6];
    const float* rge        = (const float*)d_in[7];
    const float* lin_w      = (const float*)d_in[26];
    const float* lin_b      = (const float*)d_in[27];
    float* out = (float*)d_out;

    // ---- workspace layout ----
    float* ws       = (float*)d_ws;
    float* dinv_in  = ws;                    // N
    float* dinv_out = dinv_in + N_NODES;     // N
    float* pool     = dinv_out + N_NODES;    // NG*H
    float* cnt      = pool + NG * H;         // NG
    float* relA     = cnt + NG;              // 201*H
    float* rbuf     = relA + RELROWS * H;    // 200*H
    float* lwl      = rbuf + 200 * H;        // 3*H
    float* csr_nrm  = lwl + 3 * H;           // E
    int*   rowptr   = (int*)(csr_nrm + N_EDGES);  // N+1
    int*   rfill    = rowptr + N_NODES + 1;       // N
    int*   cnt_dst  = rfill + N_NODES;            // N
    int*   meta     = cnt_dst + N_NODES;          // E
    int*   excl     = meta + N_EDGES;             // N
    int*   bsum     = excl + N_NODES;             // SCAN_NB
    int*   boff     = bsum + SCAN_NB;             // SCAN_NB (+ pad)
    unsigned* QRh   = (unsigned*)(boff + SCAN_NB + 2);  // NH uints (Q rows, then R rows), bf16 pairs
    unsigned* Sb    = QRh + (size_t)NH;                 // NH/2 uints (N x 128 bf16)
    unsigned* RWh   = Sb + (size_t)NH / 2;              // 3*400*64 uints
    unsigned short* Bpack = (unsigned short*)(RWh + 3 * 400 * 64);  // 9*16384 bf16

    hipMemsetAsync(dinv_in, 0, (size_t)(2 * N_NODES + NG * H + NG) * sizeof(float), stream);
    hipMemsetAsync(cnt_dst, 0, (size_t)N_NODES * sizeof(int), stream);

    deg_hist_kernel<<<(N_EDGES + 255) / 256, 256, 0, stream>>>(ei, dinv_in, dinv_out, cnt_dst);
    dinv_kernel    <<<(N_NODES + 255) / 256, 256, 0, stream>>>(dinv_in, dinv_out);
    scan1_kernel   <<<SCAN_NB, 1024, 0, stream>>>(cnt_dst, excl, bsum);
    scan2_kernel   <<<1, 128, 0, stream>>>(bsum, boff, rowptr);
    scan3_kernel   <<<SCAN_NB, 1024, 0, stream>>>(excl, boff, rowptr, rfill);
    fill_kernel    <<<(N_EDGES + 255) / 256, 256, 0, stream>>>(ei, etype, dinv_in, dinv_out,
                                                               rfill, meta, csr_nrm);
    cnt_bs_kernel  <<<NG / 64, 64, 0, stream>>>(batch, cnt);

    // pack all 9 weight matrices into MFMA B-frag order
    WPtrs wp;
    for (int l = 0; l < 3; l++) {
        wp.p[l * 3 + 0] = (const float*)d_in[8 + 6 * l + 0];  // wIn
        wp.p[l * 3 + 1] = (const float*)d_in[8 + 6 * l + 1];  // wOut
        wp.p[l * 3 + 2] = (const float*)d_in[8 + 6 * l + 2];  // wLoop
    }
    wpack_kernel<<<dim3(8, 9), 256, 0, stream>>>(wp, Bpack);

    // rel chain up-front
    for (int l = 0; l < 3; l++) {
        const float* wIn   = (const float*)d_in[8 + 6 * l + 0];
        const float* wOut  = (const float*)d_in[8 + 6 * l + 1];
        const float* wLoop = (const float*)d_in[8 + 6 * l + 2];
        const float* wRel  = (const float*)d_in[8 + 6 * l + 3];
        const float* lrel  = (const float*)d_in[8 + 6 * l + 4];
        rel_build_kernel<<<RELROWS, H, 0, stream>>>(rge, rbuf, lrel, relA, l + 1);
        rel_mm_kernel   <<<RELROWS, H, 0, stream>>>(relA, wIn, wOut, wRel, wLoop,
                                                    (unsigned short*)(RWh + (size_t)l * 400 * 64),
                                                    rbuf, lwl + l * H);
    }

    // three conv layers
    int mm_grid = (N_NODES + MMB - 1) / MMB;
    for (int l = 0; l < 3; l++) {
        const float* bl = (const float*)d_in[8 + 6 * l + 5];
        mm_mfma_kernel<<<mm_grid, 256, 0, stream>>>(x, (const unsigned short*)Sb, (l == 0) ? 1 : 0,
                                                    Bpack + (size_t)l * 3 * 16384, lwl + l * H,
                                                    (unsigned short*)QRh, (unsigned short*)Sb);
        gather_kernel<<<N_NODES / 4, 256, 0, stream>>>(rowptr, meta, csr_nrm,
                                                       QRh, RWh + (size_t)l * 400 * 64, bl,
                                                       Sb, batch, pool, (l == 2) ? 1 : 0);
    }

    final_kernel<<<NG, 64, 0, stream>>>(pool, cnt, rel_table, rel_labels, lin_w, lin_b, out);
}